// Round 3
// baseline (759.048 us; speedup 1.0000x reference)
//
#include <hip/hip_runtime.h>

#define BB 16
#define NO 512
#define NM 32
#define DOC 128
#define C8 1024
#define NH 64
#define KD 16

// ---------------- ws layout (float offsets), ~41 MiB total ----------------
// x12 region [0, 8388608) is reused: Uo + logits live there after x12 dies.
#define OFF_X12   0          // [16*512,1024]  x1/x2 of ext-attn (in-place)
#define OFF_UO    0          // [8192,128] (alias: x12 dead by then)
#define OFF_LOG   1048576    // [16,16384] (alias, after Uo)
#define OFF_HOPES 8388608    // [8192,128] ext-attn output
#define OFF_HOPEG 9437184    // [8192,128] GAT h_ope
#define OFF_HMAC  10485760   // [512,128]  GAT h_mac (pre)
#define OFF_HMACS 10551296   // [512,128]  GAT output
#define OFF_AO    10616832   // [8192]
#define OFF_AM    10625024   // [512]
#define OFF_PO    10625536   // [16,128]
#define OFF_PM    10627584   // [16,128]
#define OFF_UM    10629632   // [512,128]  folded U_m + U_p + Ab0
#define OFF_FLAG  10695168   // int flag (mask dtype probe)

// NOTE (determinism audit): d_out's 48 floats are each written by exactly one
// kernel per call (final_kernel: [0,16)+[32,48); critic_kernel: [16,32)); no
// kernel reads d_out; every ws word read is written earlier in the same call.

__device__ __forceinline__ float fast_tanh(float x) {
  x = fminf(15.0f, fmaxf(-15.0f, x));
  float e = __expf(2.0f * x);
  return 1.0f - 2.0f * __builtin_amdgcn_rcpf(e + 1.0f);
}

// ---------------- mask dtype probe ----------------
// int32/float32 0/1 words are in {0,1,0x3f800000}; packed bytes produce words
// like 0x00010001 with overwhelming probability over 4096 samples.
__global__ void probe_mask_kernel(const unsigned int* __restrict__ mask,
                                  int* __restrict__ flag) {
  __shared__ int s[4];
  int bad = 0;
  for (int i = threadIdx.x; i < 4096; i += 256) {
    unsigned int v = mask[i];
    if (!(v == 0u || v == 1u || v == 0x3f800000u)) bad = 1;
  }
  unsigned long long any = __ballot(bad);
  int lane = threadIdx.x & 63, w = threadIdx.x >> 6;
  if (lane == 0) s[w] = (any != 0ull) ? 1 : 0;
  __syncthreads();
  if (threadIdx.x == 0) flag[0] = s[0] | s[1] | s[2] | s[3];
}

// ---------------- generic f32 GEMM: C[m,n] = sum_k X[m,k]*W[n,k] (+bias[n]) ----------------
// M,N multiples of 64; K multiple of 32.
__global__ __launch_bounds__(256) void gemm_xt(
    const float* __restrict__ X, const float* __restrict__ W,
    const float* __restrict__ bias, float* __restrict__ C,
    int M, int N, int Kdim, int ldx, int ldw) {
  __shared__ float Xs[64][33];
  __shared__ float Ws[64][33];
  const int tid = threadIdx.x;
  const int tx = tid & 15, ty = tid >> 4;
  const int m0 = blockIdx.y * 64, n0 = blockIdx.x * 64;
  float acc[4][4] = {};
  for (int k0 = 0; k0 < Kdim; k0 += 32) {
    #pragma unroll
    for (int l = 0; l < 8; ++l) {
      int f = l * 256 + tid;
      int r = f >> 5, c = f & 31;
      Xs[r][c] = X[(m0 + r) * ldx + k0 + c];
      Ws[r][c] = W[(n0 + r) * ldw + k0 + c];
    }
    __syncthreads();
    #pragma unroll 8
    for (int kk = 0; kk < 32; ++kk) {
      float xr[4], wr[4];
      #pragma unroll
      for (int i = 0; i < 4; ++i) xr[i] = Xs[ty * 4 + i][kk];
      #pragma unroll
      for (int j = 0; j < 4; ++j) wr[j] = Ws[tx * 4 + j][kk];
      #pragma unroll
      for (int i = 0; i < 4; ++i)
        #pragma unroll
        for (int j = 0; j < 4; ++j)
          acc[i][j] = fmaf(xr[i], wr[j], acc[i][j]);
    }
    __syncthreads();
  }
  #pragma unroll
  for (int i = 0; i < 4; ++i) {
    int m = m0 + ty * 4 + i;
    #pragma unroll
    for (int j = 0; j < 4; ++j) {
      int n = n0 + tx * 4 + j;
      C[m * N + n] = acc[i][j] + (bias ? bias[n] : 0.0f);
    }
  }
}

// ---------------- external attention middle: per (b,h) slice, in place on x12 ----------------
__global__ __launch_bounds__(256) void attn_kernel(
    float* __restrict__ x12,
    const float* __restrict__ W0, const float* __restrict__ b0,
    const float* __restrict__ W1, const float* __restrict__ b1) {
  __shared__ float S[NO][KD + 1];     // 34.8 KB, holds S then A then p
  __shared__ float red[16][17];
  __shared__ float colmax[16], colsum[16];
  __shared__ float rs[NO];
  const int b = blockIdx.y, h = blockIdx.x;
  const int tid = threadIdx.x;
  const int tk = tid & 15, tg = tid >> 4;
  float* base = x12 + (b * NO) * C8 + h * KD;
  // stage S[n][k] = x1[b,n,h*16+k]
  #pragma unroll
  for (int l = 0; l < 32; ++l) {
    int f = l * 256 + tid;
    int n = f >> 4, k = f & 15;
    S[n][k] = base[n * C8 + k];
  }
  __syncthreads();
  // A[n,tk] = S[n,:] . W0[tk,:] + b0[tk], into registers
  float w0r[16];
  #pragma unroll
  for (int k = 0; k < 16; ++k) w0r[k] = W0[tk * 16 + k];
  const float b0v = b0[tk];
  float Areg[32];
  for (int i = 0; i < 32; ++i) {
    int n = tg + 16 * i;
    float acc = b0v;
    #pragma unroll
    for (int k = 0; k < 16; ++k) acc = fmaf(S[n][k], w0r[k], acc);
    Areg[i] = acc;
  }
  __syncthreads();
  for (int i = 0; i < 32; ++i) { int n = tg + 16 * i; S[n][tk] = Areg[i]; }
  __syncthreads();
  // softmax over n (per column tk)
  float mx = -1e30f;
  for (int i = 0; i < 32; ++i) mx = fmaxf(mx, Areg[i]);
  red[tg][tk] = mx;
  __syncthreads();
  if (tg == 0) {
    float mm = red[0][tk];
    for (int g = 1; g < 16; ++g) mm = fmaxf(mm, red[g][tk]);
    colmax[tk] = mm;
  }
  __syncthreads();
  const float cm = colmax[tk];
  float s = 0.f;
  for (int i = 0; i < 32; ++i) { float e = __expf(Areg[i] - cm); Areg[i] = e; s += e; }
  __syncthreads();
  red[tg][tk] = s;
  __syncthreads();
  if (tg == 0) {
    float ss = 0.f;
    for (int g = 0; g < 16; ++g) ss += red[g][tk];
    colsum[tk] = ss;
  }
  __syncthreads();
  const float inv = 1.0f / colsum[tk];
  for (int i = 0; i < 32; ++i) { int n = tg + 16 * i; S[n][tk] = Areg[i] * inv; }
  __syncthreads();
  // row sums over k (for the /(1e-10+sum) normalization)
  #pragma unroll
  for (int rr = 0; rr < 2; ++rr) {
    int n = tid * 2 + rr;
    float t = 0.f;
    #pragma unroll
    for (int k = 0; k < 16; ++k) t += S[n][k];
    rs[n] = t;
  }
  __syncthreads();
  // out[n,tk] = (p[n,:]/(1e-10+rs[n])) . W1[tk,:] + b1[tk] -> write back in place
  float w1r[16];
  #pragma unroll
  for (int k = 0; k < 16; ++k) w1r[k] = W1[tk * 16 + k];
  const float b1v = b1[tk];
  for (int i = 0; i < 32; ++i) {
    int n = tg + 16 * i;
    float rinv = 1.0f / (1e-10f + rs[n]);
    float acc = b1v;
    #pragma unroll
    for (int k = 0; k < 16; ++k) acc = fmaf(S[n][k] * rinv, w1r[k], acc);
    base[n * C8 + tk] = acc;
  }
}

// ---------------- row dot with alpha (a_o / a_m) : one wave per row ----------------
__global__ void rowdot(const float* __restrict__ X, const float* __restrict__ alpha,
                       float* __restrict__ out, int R) {
  int wid = (blockIdx.x * blockDim.x + threadIdx.x) >> 6;
  int lane = threadIdx.x & 63;
  if (wid >= R) return;
  const float* row = X + wid * 128;
  float v = fmaf(row[lane], alpha[lane], row[lane + 64] * alpha[lane + 64]);
  #pragma unroll
  for (int off = 32; off; off >>= 1) v += __shfl_down(v, off);
  if (lane == 0) out[wid] = v;
}

// ---------------- GAT per (b,m): masked column softmax over o + aggregation ----------------
__global__ __launch_bounds__(128) void gat_kernel(
    const float* __restrict__ adj, const float* __restrict__ ao,
    const float* __restrict__ am, const float* __restrict__ hopeG,
    const float* __restrict__ hmac, float* __restrict__ hmacs) {
  __shared__ float al[NO];
  __shared__ float sc[2];
  const int b = blockIdx.y, m = blockIdx.x;
  const int tid = threadIdx.x;
  const int lane = tid & 63, w = tid >> 6;
  const float amv = am[b * NM + m];
  float ev[4], adjv[4];
  float mx = -1e30f;
  #pragma unroll
  for (int i = 0; i < 4; ++i) {
    int o = tid + i * 128;
    float a = adj[(b * NO + o) * NM + m];
    adjv[i] = a;
    float e = ao[b * NO + o] + amv;
    e = (e >= 0.f) ? e : 0.2f * e;
    ev[i] = e;
    if (a == 1.0f) mx = fmaxf(mx, e);
  }
  #pragma unroll
  for (int off = 32; off; off >>= 1) mx = fmaxf(mx, __shfl_down(mx, off));
  if (lane == 0) sc[w] = mx;
  __syncthreads();
  mx = fmaxf(sc[0], sc[1]);
  float s = 0.f;
  float pv[4];
  #pragma unroll
  for (int i = 0; i < 4; ++i) {
    float p = (adjv[i] == 1.0f) ? __expf(ev[i] - mx) : 0.f;
    pv[i] = p; s += p;
  }
  #pragma unroll
  for (int off = 32; off; off >>= 1) s += __shfl_down(s, off);
  __syncthreads();
  if (lane == 0) sc[w] = s;
  __syncthreads();
  s = sc[0] + sc[1];
  const float sinv = (s > 0.f) ? 1.0f / s : 0.f;
  #pragma unroll
  for (int i = 0; i < 4; ++i) al[tid + i * 128] = pv[i] * sinv;
  __syncthreads();
  // aggregate: d = tid (128 dims)
  float acc = 0.f;
  for (int o = 0; o < NO; ++o) acc = fmaf(al[o], hopeG[(b * NO + o) * DOC + tid], acc);
  hmacs[(b * NM + m) * DOC + tid] = acc + hmac[(b * NM + m) * DOC + tid];
}

// ---------------- mean-pool over rows ----------------
__global__ void pool_kernel(const float* __restrict__ X, float* __restrict__ out,
                            int R, float inv) {
  int b = blockIdx.x, d = threadIdx.x;  // 128 threads
  float acc = 0.f;
  for (int r = 0; r < R; ++r) acc += X[(b * R + r) * 128 + d];
  out[b * 128 + d] = acc * inv;
}

// ---------------- folded U_m[b,m,:] = A0[:,128:512] . concat(hmacs, po, pm) + Ab0 ----------------
__global__ __launch_bounds__(128) void um_kernel(
    const float* __restrict__ hmacs, const float* __restrict__ po,
    const float* __restrict__ pm, const float* __restrict__ A0,
    const float* __restrict__ Ab0, float* __restrict__ um) {
  __shared__ float v[384];
  const int b = blockIdx.y, m = blockIdx.x;
  const int j = threadIdx.x;
  v[j] = hmacs[(b * NM + m) * 128 + j];
  v[128 + j] = po[b * 128 + j];
  v[256 + j] = pm[b * 128 + j];
  __syncthreads();
  const float* a = A0 + j * 512 + 128;
  float acc = Ab0[j];
  for (int k = 0; k < 384; ++k) acc = fmaf(a[k], v[k], acc);
  um[(b * NM + m) * 128 + j] = acc;
}

// ---------------- actor: z1=tanh(Uo+Um); logits = A2 . tanh(A1 z1 + Ab1) + Ab2 ----------------
// 64 rows per block (same b,m). LDS 50 KB -> 3 blocks/CU.
__global__ __launch_bounds__(256) void actor_kernel(
    const float* __restrict__ Uo, const float* __restrict__ Um,
    const float* __restrict__ A1, const float* __restrict__ Ab1,
    const float* __restrict__ A2, const float* __restrict__ Ab2,
    float* __restrict__ logits) {
  __shared__ float Z1s[64][129];
  __shared__ float A1s[64][65];
  __shared__ float umv[128];
  const int tid = threadIdx.x;
  const int tx = tid & 15, ty = tid >> 4;
  const int rbase = blockIdx.x * 64;       // flat row = b*16384 + m*512 + o
  const int b = rbase >> 14;
  const int rem = rbase & 16383;
  const int m = rem >> 9;
  const int obase = rem & 511;
  if (tid < 128) umv[tid] = Um[(b * NM + m) * 128 + tid];
  __syncthreads();
  const float* uo = Uo + (b * NO + obase) * 128;
  #pragma unroll
  for (int l = 0; l < 32; ++l) {
    int f = l * 256 + tid;
    int r = f >> 7, k = f & 127;
    Z1s[r][k] = fast_tanh(uo[r * 128 + k] + umv[k]);
  }
  float part[4] = {0.f, 0.f, 0.f, 0.f};
  for (int jh = 0; jh < 2; ++jh) {
    float acc[4][4] = {};
    for (int kh = 0; kh < 2; ++kh) {
      __syncthreads();
      #pragma unroll
      for (int l = 0; l < 16; ++l) {
        int f = l * 256 + tid;
        int c = f >> 6, k = f & 63;
        A1s[c][k] = A1[(jh * 64 + c) * 128 + kh * 64 + k];
      }
      __syncthreads();
      #pragma unroll 4
      for (int kk = 0; kk < 64; ++kk) {
        int kg = kh * 64 + kk;
        float xr[4], wr[4];
        #pragma unroll
        for (int i = 0; i < 4; ++i) xr[i] = Z1s[ty * 4 + i][kg];
        #pragma unroll
        for (int j = 0; j < 4; ++j) wr[j] = A1s[tx * 4 + j][kk];
        #pragma unroll
        for (int i = 0; i < 4; ++i)
          #pragma unroll
          for (int j = 0; j < 4; ++j)
            acc[i][j] = fmaf(xr[i], wr[j], acc[i][j]);
      }
    }
    #pragma unroll
    for (int j = 0; j < 4; ++j) {
      int col = jh * 64 + tx * 4 + j;
      float ab = Ab1[col], a2 = A2[col];
      #pragma unroll
      for (int i = 0; i < 4; ++i) {
        float z2 = fast_tanh(acc[i][j] + ab);
        part[i] = fmaf(a2, z2, part[i]);
      }
    }
  }
  #pragma unroll
  for (int i = 0; i < 4; ++i) {
    float v = part[i];
    #pragma unroll
    for (int off = 1; off < 16; off <<= 1) v += __shfl_xor(v, off, 16);
    if (tx == 0) logits[rbase + ty * 4 + i] = v + Ab2[0];
  }
}

// ---------------- masked log-softmax + gather + entropy (per batch) ----------------
__global__ __launch_bounds__(256) void final_kernel(
    const float* __restrict__ logits, const void* __restrict__ maskp,
    const int* __restrict__ aidx, const int* __restrict__ flag,
    float* __restrict__ out) {
  __shared__ float sc[4], sc2[4];
  const int b = blockIdx.x;
  const int tid = threadIdx.x;
  const int lane = tid & 63, w = tid >> 6;
  const bool word_mode = (flag[0] == 0);
  const unsigned int* mw = (const unsigned int*)maskp;
  const unsigned char* mb = (const unsigned char*)maskp;
  const float* lg = logits + b * (NM * NO);
  float mx = -1e30f;
  for (int s = 0; s < 64; ++s) {
    int i = s * 256 + tid;
    int o = i & 511, mm = i >> 9;
    int mofs = (b * NO + o) * NM + mm;
    bool msk = word_mode ? (mw[mofs] != 0u) : (mb[mofs] != 0);
    if (msk) mx = fmaxf(mx, lg[i]);
  }
  #pragma unroll
  for (int off = 32; off; off >>= 1) mx = fmaxf(mx, __shfl_down(mx, off));
  if (lane == 0) sc[w] = mx;
  __syncthreads();
  mx = fmaxf(fmaxf(sc[0], sc[1]), fmaxf(sc[2], sc[3]));
  __syncthreads();
  float S = 0.f, T = 0.f;
  for (int s = 0; s < 64; ++s) {
    int i = s * 256 + tid;
    int o = i & 511, mm = i >> 9;
    int mofs = (b * NO + o) * NM + mm;
    bool msk = word_mode ? (mw[mofs] != 0u) : (mb[mofs] != 0);
    if (msk) {
      float d = lg[i] - mx;
      float e = __expf(d);
      S += e;
      T = fmaf(e, d, T);
    }
  }
  #pragma unroll
  for (int off = 32; off; off >>= 1) { S += __shfl_down(S, off); T += __shfl_down(T, off); }
  if (lane == 0) { sc[w] = S; sc2[w] = T; }
  __syncthreads();
  if (tid == 0) {
    float St = sc[0] + sc[1] + sc[2] + sc[3];
    float Tt = sc2[0] + sc2[1] + sc2[2] + sc2[3];
    float lS = logf(St);
    out[b] = lg[aidx[b]] - mx - lS;          // action_logprobs
    out[32 + b] = lS - Tt / St;              // dist_entropys
  }
}

// ---------------- critic MLP (per batch) ----------------
__global__ __launch_bounds__(128) void critic_kernel(
    const float* __restrict__ po, const float* __restrict__ pm,
    const float* __restrict__ C0, const float* __restrict__ Cb0,
    const float* __restrict__ C1, const float* __restrict__ Cb1,
    const float* __restrict__ C2, const float* __restrict__ Cb2,
    float* __restrict__ out) {
  __shared__ float v[256];
  __shared__ float z[128];
  __shared__ float sc[2];
  const int b = blockIdx.x;
  const int j = threadIdx.x;
  v[j] = po[b * 128 + j];
  v[128 + j] = pm[b * 128 + j];
  __syncthreads();
  float acc = Cb0[j];
  for (int k = 0; k < 256; ++k) acc = fmaf(C0[j * 256 + k], v[k], acc);
  z[j] = fast_tanh(acc);
  __syncthreads();
  acc = Cb1[j];
  for (int k = 0; k < 128; ++k) acc = fmaf(C1[j * 128 + k], z[k], acc);
  float z2 = fast_tanh(acc);
  float p = C2[j] * z2;
  #pragma unroll
  for (int off = 32; off; off >>= 1) p += __shfl_down(p, off);
  const int lane = j & 63, w = j >> 6;
  if (lane == 0) sc[w] = p;
  __syncthreads();
  if (j == 0) out[16 + b] = sc[0] + sc[1] + Cb2[0];   // state_values
}

extern "C" void kernel_launch(void* const* d_in, const int* in_sizes, int n_in,
                              void* d_out, int out_size, void* d_ws, size_t ws_size,
                              hipStream_t stream) {
  (void)in_sizes; (void)n_in; (void)out_size; (void)ws_size;
  const float* adj  = (const float*)d_in[0];
  const float* nop  = (const float*)d_in[1];
  const float* nmac = (const float*)d_in[2];
  const void*  maskp = d_in[3];
  const int*   aidx = (const int*)d_in[4];
  const float* Wtr  = (const float*)d_in[5];
  const float* btr  = (const float*)d_in[6];
  const float* W0   = (const float*)d_in[7];
  const float* b0   = (const float*)d_in[8];
  const float* W1   = (const float*)d_in[9];
  const float* b1   = (const float*)d_in[10];
  const float* Wp   = (const float*)d_in[11];
  const float* bp   = (const float*)d_in[12];
  const float* Wo   = (const float*)d_in[13];
  const float* Wm   = (const float*)d_in[14];
  const float* alo  = (const float*)d_in[15];
  const float* alm  = (const float*)d_in[16];
  const float* A0   = (const float*)d_in[17];
  const float* Ab0  = (const float*)d_in[18];
  const float* A1   = (const float*)d_in[19];
  const float* Ab1  = (const float*)d_in[20];
  const float* A2   = (const float*)d_in[21];
  const float* Ab2  = (const float*)d_in[22];
  const float* C0   = (const float*)d_in[23];
  const float* Cb0  = (const float*)d_in[24];
  const float* C1   = (const float*)d_in[25];
  const float* Cb1  = (const float*)d_in[26];
  const float* C2   = (const float*)d_in[27];
  const float* Cb2  = (const float*)d_in[28];

  float* ws     = (float*)d_ws;        // needs ~41 MiB
  float* x12    = ws + OFF_X12;
  float* hopes  = ws + OFF_HOPES;
  float* hopeG  = ws + OFF_HOPEG;
  float* hmac   = ws + OFF_HMAC;
  float* hmacs  = ws + OFF_HMACS;
  float* ao     = ws + OFF_AO;
  float* am     = ws + OFF_AM;
  float* po     = ws + OFF_PO;
  float* pm     = ws + OFF_PM;
  float* Uo     = ws + OFF_UO;
  float* Um     = ws + OFF_UM;
  float* logits = ws + OFF_LOG;
  int*   flag   = (int*)(ws + OFF_FLAG);
  float* outp   = (float*)d_out;

  probe_mask_kernel<<<1, 256, 0, stream>>>((const unsigned int*)maskp, flag);

  // external attention
  gemm_xt<<<dim3(16, 128), 256, 0, stream>>>(nop, Wtr, btr, x12, 8192, 1024, 128, 128, 128);
  attn_kernel<<<dim3(NH, BB), 256, 0, stream>>>(x12, W0, b0, W1, b1);
  gemm_xt<<<dim3(2, 128), 256, 0, stream>>>(x12, Wp, bp, hopes, 8192, 128, 1024, 1024, 1024);

  // GAT
  gemm_xt<<<dim3(2, 128), 256, 0, stream>>>(nop, Wo, nullptr, hopeG, 8192, 128, 128, 128, 128);
  gemm_xt<<<dim3(2, 8), 256, 0, stream>>>(nmac, Wm, nullptr, hmac, 512, 128, 64, 64, 64);
  rowdot<<<2048, 256, 0, stream>>>(hopeG, alo, ao, 8192);
  rowdot<<<128, 256, 0, stream>>>(hmac, alm, am, 512);
  gat_kernel<<<dim3(NM, BB), 128, 0, stream>>>(adj, ao, am, hopeG, hmac, hmacs);

  // pooling
  pool_kernel<<<16, 128, 0, stream>>>(hopes, po, 512, 1.0f / 512.0f);
  pool_kernel<<<16, 128, 0, stream>>>(hmacs, pm, 32, 1.0f / 32.0f);

  // actor (Uo aliases x12's region — x12 is dead after the proj GEMM above)
  gemm_xt<<<dim3(2, 128), 256, 0, stream>>>(hopes, A0, nullptr, Uo, 8192, 128, 128, 128, 512);
  um_kernel<<<dim3(NM, BB), 128, 0, stream>>>(hmacs, po, pm, A0, Ab0, Um);
  actor_kernel<<<4096, 256, 0, stream>>>(Uo, Um, A1, Ab1, A2, Ab2, logits);
  final_kernel<<<16, 256, 0, stream>>>(logits, maskp, aidx, flag, outp);

  // critic
  critic_kernel<<<16, 128, 0, stream>>>(po, pm, C0, Cb0, C1, Cb1, C2, Cb2, outp);
}

// Round 6
// 500.388 us; speedup vs baseline: 1.5169x; 1.5169x over previous
//
#include <hip/hip_runtime.h>

#define BB 16
#define NO 512
#define NM 32
#define DOC 128
#define C8 1024
#define NH 64
#define KD 16

// ---------------- ws layout (float offsets), ~41 MiB total ----------------
// x12 region [0, 8388608) is reused: Uo + logits live there after x12 dies.
#define OFF_X12   0          // [16*512,1024]  x1/x2 of ext-attn (in-place)
#define OFF_UO    0          // [8192,128] (alias: x12 dead by then)
#define OFF_LOG   1048576    // [16,16384] (alias, after Uo)
#define OFF_HOPES 8388608    // [8192,128] ext-attn output
#define OFF_HOPEG 9437184    // [8192,128] GAT h_ope
#define OFF_HMAC  10485760   // [512,128]  GAT h_mac (pre)
#define OFF_HMACS 10551296   // [512,128]  GAT output
#define OFF_AO    10616832   // [8192]
#define OFF_AM    10625024   // [512]
#define OFF_PO    10625536   // [16,128]
#define OFF_PM    10627584   // [16,128]
#define OFF_UM    10629632   // [512,128]  folded U_m + U_p + Ab0
#define OFF_FLAG  10695168   // int flag (mask dtype probe)

using f32x4  = __attribute__((ext_vector_type(4))) float;
using s16x4  = __attribute__((ext_vector_type(4))) short;
using bf16x8 = __attribute__((ext_vector_type(8))) short;   // 8 bf16 (4 VGPRs)

__device__ __forceinline__ float fast_tanh(float x) {
  x = fminf(15.0f, fmaxf(-15.0f, x));
  float e = __expf(2.0f * x);
  return 1.0f - 2.0f * __builtin_amdgcn_rcpf(e + 1.0f);
}

__device__ __forceinline__ short f2bf(float f) {          // RNE f32->bf16
  unsigned u = __builtin_bit_cast(unsigned, f);
  u += 0x7FFFu + ((u >> 16) & 1u);
  return (short)(u >> 16);
}

// ---------------- mask dtype probe ----------------
__global__ void probe_mask_kernel(const unsigned int* __restrict__ mask,
                                  int* __restrict__ flag) {
  __shared__ int s[4];
  int bad = 0;
  for (int i = threadIdx.x; i < 4096; i += 256) {
    unsigned int v = mask[i];
    if (!(v == 0u || v == 1u || v == 0x3f800000u)) bad = 1;
  }
  unsigned long long any = __ballot(bad);
  int lane = threadIdx.x & 63, w = threadIdx.x >> 6;
  if (lane == 0) s[w] = (any != 0ull) ? 1 : 0;
  __syncthreads();
  if (threadIdx.x == 0) flag[0] = s[0] | s[1] | s[2] | s[3];
}

// ---------------- generic f32 GEMM: C[m,n] = sum_k X[m,k]*W[n,k] (+bias[n]) ----------------
__global__ __launch_bounds__(256) void gemm_xt(
    const float* __restrict__ X, const float* __restrict__ W,
    const float* __restrict__ bias, float* __restrict__ C,
    int M, int N, int Kdim, int ldx, int ldw) {
  __shared__ float Xs[64][33];
  __shared__ float Ws[64][33];
  const int tid = threadIdx.x;
  const int tx = tid & 15, ty = tid >> 4;
  const int m0 = blockIdx.y * 64, n0 = blockIdx.x * 64;
  float acc[4][4] = {};
  for (int k0 = 0; k0 < Kdim; k0 += 32) {
    #pragma unroll
    for (int l = 0; l < 8; ++l) {
      int f = l * 256 + tid;
      int r = f >> 5, c = f & 31;
      Xs[r][c] = X[(m0 + r) * ldx + k0 + c];
      Ws[r][c] = W[(n0 + r) * ldw + k0 + c];
    }
    __syncthreads();
    #pragma unroll 8
    for (int kk = 0; kk < 32; ++kk) {
      float xr[4], wr[4];
      #pragma unroll
      for (int i = 0; i < 4; ++i) xr[i] = Xs[ty * 4 + i][kk];
      #pragma unroll
      for (int j = 0; j < 4; ++j) wr[j] = Ws[tx * 4 + j][kk];
      #pragma unroll
      for (int i = 0; i < 4; ++i)
        #pragma unroll
        for (int j = 0; j < 4; ++j)
          acc[i][j] = fmaf(xr[i], wr[j], acc[i][j]);
    }
    __syncthreads();
  }
  #pragma unroll
  for (int i = 0; i < 4; ++i) {
    int m = m0 + ty * 4 + i;
    #pragma unroll
    for (int j = 0; j < 4; ++j) {
      int n = n0 + tx * 4 + j;
      C[m * N + n] = acc[i][j] + (bias ? bias[n] : 0.0f);
    }
  }
}

// ---------------- external attention middle: per (b,h) slice, in place on x12 ----------------
__global__ __launch_bounds__(256) void attn_kernel(
    float* __restrict__ x12,
    const float* __restrict__ W0, const float* __restrict__ b0,
    const float* __restrict__ W1, const float* __restrict__ b1) {
  __shared__ float S[NO][KD + 1];
  __shared__ float red[16][17];
  __shared__ float colmax[16], colsum[16];
  __shared__ float rs[NO];
  const int b = blockIdx.y, h = blockIdx.x;
  const int tid = threadIdx.x;
  const int tk = tid & 15, tg = tid >> 4;
  float* base = x12 + (b * NO) * C8 + h * KD;
  #pragma unroll
  for (int l = 0; l < 32; ++l) {
    int f = l * 256 + tid;
    int n = f >> 4, k = f & 15;
    S[n][k] = base[n * C8 + k];
  }
  __syncthreads();
  float w0r[16];
  #pragma unroll
  for (int k = 0; k < 16; ++k) w0r[k] = W0[tk * 16 + k];
  const float b0v = b0[tk];
  float Areg[32];
  for (int i = 0; i < 32; ++i) {
    int n = tg + 16 * i;
    float acc = b0v;
    #pragma unroll
    for (int k = 0; k < 16; ++k) acc = fmaf(S[n][k], w0r[k], acc);
    Areg[i] = acc;
  }
  __syncthreads();
  for (int i = 0; i < 32; ++i) { int n = tg + 16 * i; S[n][tk] = Areg[i]; }
  __syncthreads();
  float mx = -1e30f;
  for (int i = 0; i < 32; ++i) mx = fmaxf(mx, Areg[i]);
  red[tg][tk] = mx;
  __syncthreads();
  if (tg == 0) {
    float mm = red[0][tk];
    for (int g = 1; g < 16; ++g) mm = fmaxf(mm, red[g][tk]);
    colmax[tk] = mm;
  }
  __syncthreads();
  const float cm = colmax[tk];
  float s = 0.f;
  for (int i = 0; i < 32; ++i) { float e = __expf(Areg[i] - cm); Areg[i] = e; s += e; }
  __syncthreads();
  red[tg][tk] = s;
  __syncthreads();
  if (tg == 0) {
    float ss = 0.f;
    for (int g = 0; g < 16; ++g) ss += red[g][tk];
    colsum[tk] = ss;
  }
  __syncthreads();
  const float inv = 1.0f / colsum[tk];
  for (int i = 0; i < 32; ++i) { int n = tg + 16 * i; S[n][tk] = Areg[i] * inv; }
  __syncthreads();
  #pragma unroll
  for (int rr = 0; rr < 2; ++rr) {
    int n = tid * 2 + rr;
    float t = 0.f;
    #pragma unroll
    for (int k = 0; k < 16; ++k) t += S[n][k];
    rs[n] = t;
  }
  __syncthreads();
  float w1r[16];
  #pragma unroll
  for (int k = 0; k < 16; ++k) w1r[k] = W1[tk * 16 + k];
  const float b1v = b1[tk];
  for (int i = 0; i < 32; ++i) {
    int n = tg + 16 * i;
    float rinv = 1.0f / (1e-10f + rs[n]);
    float acc = b1v;
    #pragma unroll
    for (int k = 0; k < 16; ++k) acc = fmaf(S[n][k] * rinv, w1r[k], acc);
    base[n * C8 + tk] = acc;
  }
}

// ---------------- row dot with alpha (a_o / a_m) ----------------
__global__ void rowdot(const float* __restrict__ X, const float* __restrict__ alpha,
                       float* __restrict__ out, int R) {
  int wid = (blockIdx.x * blockDim.x + threadIdx.x) >> 6;
  int lane = threadIdx.x & 63;
  if (wid >= R) return;
  const float* row = X + wid * 128;
  float v = fmaf(row[lane], alpha[lane], row[lane + 64] * alpha[lane + 64]);
  #pragma unroll
  for (int off = 32; off; off >>= 1) v += __shfl_down(v, off);
  if (lane == 0) out[wid] = v;
}

// ---------------- GAT per (b,m) ----------------
__global__ __launch_bounds__(128) void gat_kernel(
    const float* __restrict__ adj, const float* __restrict__ ao,
    const float* __restrict__ am, const float* __restrict__ hopeG,
    const float* __restrict__ hmac, float* __restrict__ hmacs) {
  __shared__ float al[NO];
  __shared__ float sc[2];
  const int b = blockIdx.y, m = blockIdx.x;
  const int tid = threadIdx.x;
  const int lane = tid & 63, w = tid >> 6;
  const float amv = am[b * NM + m];
  float ev[4], adjv[4];
  float mx = -1e30f;
  #pragma unroll
  for (int i = 0; i < 4; ++i) {
    int o = tid + i * 128;
    float a = adj[(b * NO + o) * NM + m];
    adjv[i] = a;
    float e = ao[b * NO + o] + amv;
    e = (e >= 0.f) ? e : 0.2f * e;
    ev[i] = e;
    if (a == 1.0f) mx = fmaxf(mx, e);
  }
  #pragma unroll
  for (int off = 32; off; off >>= 1) mx = fmaxf(mx, __shfl_down(mx, off));
  if (lane == 0) sc[w] = mx;
  __syncthreads();
  mx = fmaxf(sc[0], sc[1]);
  float s = 0.f;
  float pv[4];
  #pragma unroll
  for (int i = 0; i < 4; ++i) {
    float p = (adjv[i] == 1.0f) ? __expf(ev[i] - mx) : 0.f;
    pv[i] = p; s += p;
  }
  #pragma unroll
  for (int off = 32; off; off >>= 1) s += __shfl_down(s, off);
  __syncthreads();
  if (lane == 0) sc[w] = s;
  __syncthreads();
  s = sc[0] + sc[1];
  const float sinv = (s > 0.f) ? 1.0f / s : 0.f;
  #pragma unroll
  for (int i = 0; i < 4; ++i) al[tid + i * 128] = pv[i] * sinv;
  __syncthreads();
  float acc = 0.f;
  for (int o = 0; o < NO; ++o) acc = fmaf(al[o], hopeG[(b * NO + o) * DOC + tid], acc);
  hmacs[(b * NM + m) * DOC + tid] = acc + hmac[(b * NM + m) * DOC + tid];
}

// ---------------- mean-pool over rows (512 threads: 4-way row split) ----------------
__global__ __launch_bounds__(512) void pool_kernel(const float* __restrict__ X,
                                                   float* __restrict__ out,
                                                   int R, float inv) {
  __shared__ float part[4][128];
  const int b = blockIdx.x;
  const int d = threadIdx.x & 127, g = threadIdx.x >> 7;
  const int per = R >> 2;
  float acc = 0.f;
  for (int r = g * per; r < (g + 1) * per; ++r) acc += X[(b * R + r) * 128 + d];
  part[g][d] = acc;
  __syncthreads();
  if (g == 0)
    out[b * 128 + d] = (part[0][d] + part[1][d] + part[2][d] + part[3][d]) * inv;
}

// ---------------- folded U_m ----------------
__global__ __launch_bounds__(128) void um_kernel(
    const float* __restrict__ hmacs, const float* __restrict__ po,
    const float* __restrict__ pm, const float* __restrict__ A0,
    const float* __restrict__ Ab0, float* __restrict__ um) {
  __shared__ float v[384];
  const int b = blockIdx.y, m = blockIdx.x;
  const int j = threadIdx.x;
  v[j] = hmacs[(b * NM + m) * 128 + j];
  v[128 + j] = po[b * 128 + j];
  v[256 + j] = pm[b * 128 + j];
  __syncthreads();
  const float* a = A0 + j * 512 + 128;
  float acc = Ab0[j];
  for (int k = 0; k < 384; ++k) acc = fmaf(a[k], v[k], acc);
  um[(b * NM + m) * 128 + j] = acc;
}

// ---------------- actor via bf16 MFMA 16x16x32 ----------------
// Block = 64 rows (4 waves x 16 rows), all same (b,m).
// A1 staged in LDS as bf16 [128][136] (pad keeps b128 reads 16B-aligned,
// slot-balanced: 8 lanes / 16B-slot = b128 minimum).
// a-frag built in registers: lane holds Z1[row=lane&15][k=kk*32+(lane>>4)*8..+7].
// b-frag: lane holds A1[col=ct*16+(lane&15)][same k] (16B contiguous in LDS).
// D (m89): col=lane&15, row=(lane>>4)*4+reg.
__global__ __launch_bounds__(256) void actor_mfma_kernel(
    const float* __restrict__ Uo, const float* __restrict__ Um,
    const float* __restrict__ A1, const float* __restrict__ Ab1,
    const float* __restrict__ A2, const float* __restrict__ Ab2,
    float* __restrict__ logits) {
  __shared__ short a1s[128 * 136];
  __shared__ float umv[128];
  const int tid = threadIdx.x;
  const int rbase = blockIdx.x * 64;       // flat row = b*16384 + m*512 + o
  const int b = rbase >> 14;
  const int m = (rbase & 16383) >> 9;
  // stage A1 -> LDS bf16 (thread handles 4 consecutive k per iter)
  #pragma unroll
  for (int it = 0; it < 16; ++it) {
    int f = it * 1024 + tid * 4;
    int c = f >> 7, k = f & 127;
    f32x4 v = *(const f32x4*)(A1 + c * 128 + k);
    s16x4 sv;
    sv[0] = f2bf(v[0]); sv[1] = f2bf(v[1]); sv[2] = f2bf(v[2]); sv[3] = f2bf(v[3]);
    *(s16x4*)&a1s[c * 136 + k] = sv;
  }
  if (tid < 128) umv[tid] = Um[(b * NM + m) * 128 + tid];
  __syncthreads();

  const int lane = tid & 63, w = tid >> 6;
  const int rowl = lane & 15, kg = lane >> 4;
  const float* uo = Uo + (rbase + w * 16 + rowl) * 128;
  // build 4 a-frags (z1 = tanh(Uo+Um) in bf16)
  bf16x8 af[4];
  #pragma unroll
  for (int kk = 0; kk < 4; ++kk) {
    int kb = kk * 32 + kg * 8;
    f32x4 u0 = *(const f32x4*)(uo + kb);
    f32x4 u1 = *(const f32x4*)(uo + kb + 4);
    #pragma unroll
    for (int e = 0; e < 4; ++e) af[kk][e]     = f2bf(fast_tanh(u0[e] + umv[kb + e]));
    #pragma unroll
    for (int e = 0; e < 4; ++e) af[kk][4 + e] = f2bf(fast_tanh(u1[e] + umv[kb + 4 + e]));
  }
  // 8 col-tiles x 4 K-steps; epilogue (tanh + A2 dot) fused per tile
  float partrow[4] = {0.f, 0.f, 0.f, 0.f};
  #pragma unroll
  for (int ct = 0; ct < 8; ++ct) {
    f32x4 acc = {0.f, 0.f, 0.f, 0.f};
    #pragma unroll
    for (int kk = 0; kk < 4; ++kk) {
      bf16x8 bf = *(const bf16x8*)&a1s[(ct * 16 + rowl) * 136 + kk * 32 + kg * 8];
      acc = __builtin_amdgcn_mfma_f32_16x16x32_bf16(af[kk], bf, acc, 0, 0, 0);
    }
    const int col = ct * 16 + rowl;
    const float ab = Ab1[col], a2c = A2[col];
    #pragma unroll
    for (int r = 0; r < 4; ++r) {
      float z2 = fast_tanh(acc[r] + ab);
      partrow[r] = fmaf(a2c, z2, partrow[r]);
    }
  }
  // reduce over the 16 cols held by lanes sharing kg; write 16 rows/wave
  const float ab2 = Ab2[0];
  #pragma unroll
  for (int r = 0; r < 4; ++r) {
    float v = partrow[r];
    #pragma unroll
    for (int off = 1; off < 16; off <<= 1) v += __shfl_xor(v, off);
    if (rowl == 0) logits[rbase + w * 16 + kg * 4 + r] = v + ab2;
  }
}

// ---------------- masked log-softmax + gather + entropy (1024 threads) ----------------
__global__ __launch_bounds__(1024) void final_kernel(
    const float* __restrict__ logits, const void* __restrict__ maskp,
    const int* __restrict__ aidx, const int* __restrict__ flag,
    float* __restrict__ out) {
  __shared__ float sc[16], sc2[16];
  const int b = blockIdx.x;
  const int tid = threadIdx.x;
  const int lane = tid & 63, w = tid >> 6;
  const bool word_mode = (flag[0] == 0);
  const unsigned int* mw = (const unsigned int*)maskp;
  const unsigned char* mb = (const unsigned char*)maskp;
  const float* lg = logits + b * (NM * NO);
  float mx = -1e30f;
  for (int s = 0; s < 16; ++s) {
    int i = s * 1024 + tid;
    int o = i & 511, mm = i >> 9;
    int mofs = (b * NO + o) * NM + mm;
    bool msk = word_mode ? (mw[mofs] != 0u) : (mb[mofs] != 0);
    if (msk) mx = fmaxf(mx, lg[i]);
  }
  #pragma unroll
  for (int off = 32; off; off >>= 1) mx = fmaxf(mx, __shfl_down(mx, off));
  if (lane == 0) sc[w] = mx;
  __syncthreads();
  if (tid == 0) {
    float m2 = sc[0];
    for (int k = 1; k < 16; ++k) m2 = fmaxf(m2, sc[k]);
    sc[0] = m2;
  }
  __syncthreads();
  mx = sc[0];
  __syncthreads();
  float S = 0.f, T = 0.f;
  for (int s = 0; s < 16; ++s) {
    int i = s * 1024 + tid;
    int o = i & 511, mm = i >> 9;
    int mofs = (b * NO + o) * NM + mm;
    bool msk = word_mode ? (mw[mofs] != 0u) : (mb[mofs] != 0);
    if (msk) {
      float d = lg[i] - mx;
      float e = __expf(d);
      S += e;
      T = fmaf(e, d, T);
    }
  }
  #pragma unroll
  for (int off = 32; off; off >>= 1) { S += __shfl_down(S, off); T += __shfl_down(T, off); }
  if (lane == 0) { sc[w] = S; sc2[w] = T; }
  __syncthreads();
  if (tid == 0) {
    float St = 0.f, Tt = 0.f;
    for (int k = 0; k < 16; ++k) { St += sc[k]; Tt += sc2[k]; }
    float lS = logf(St);
    out[b] = lg[aidx[b]] - mx - lS;          // action_logprobs
    out[32 + b] = lS - Tt / St;              // dist_entropys
  }
}

// ---------------- critic MLP (per batch) ----------------
__global__ __launch_bounds__(128) void critic_kernel(
    const float* __restrict__ po, const float* __restrict__ pm,
    const float* __restrict__ C0, const float* __restrict__ Cb0,
    const float* __restrict__ C1, const float* __restrict__ Cb1,
    const float* __restrict__ C2, const float* __restrict__ Cb2,
    float* __restrict__ out) {
  __shared__ float v[256];
  __shared__ float z[128];
  __shared__ float sc[2];
  const int b = blockIdx.x;
  const int j = threadIdx.x;
  v[j] = po[b * 128 + j];
  v[128 + j] = pm[b * 128 + j];
  __syncthreads();
  float acc = Cb0[j];
  for (int k = 0; k < 256; ++k) acc = fmaf(C0[j * 256 + k], v[k], acc);
  z[j] = fast_tanh(acc);
  __syncthreads();
  acc = Cb1[j];
  for (int k = 0; k < 128; ++k) acc = fmaf(C1[j * 128 + k], z[k], acc);
  float z2 = fast_tanh(acc);
  float p = C2[j] * z2;
  #pragma unroll
  for (int off = 32; off; off >>= 1) p += __shfl_down(p, off);
  const int lane = j & 63, w = j >> 6;
  if (lane == 0) sc[w] = p;
  __syncthreads();
  if (j == 0) out[16 + b] = sc[0] + sc[1] + Cb2[0];   // state_values
}

extern "C" void kernel_launch(void* const* d_in, const int* in_sizes, int n_in,
                              void* d_out, int out_size, void* d_ws, size_t ws_size,
                              hipStream_t stream) {
  (void)in_sizes; (void)n_in; (void)out_size; (void)ws_size;
  const float* adj  = (const float*)d_in[0];
  const float* nop  = (const float*)d_in[1];
  const float* nmac = (const float*)d_in[2];
  const void*  maskp = d_in[3];
  const int*   aidx = (const int*)d_in[4];
  const float* Wtr  = (const float*)d_in[5];
  const float* btr  = (const float*)d_in[6];
  const float* W0   = (const float*)d_in[7];
  const float* b0   = (const float*)d_in[8];
  const float* W1   = (const float*)d_in[9];
  const float* b1   = (const float*)d_in[10];
  const float* Wp   = (const float*)d_in[11];
  const float* bp   = (const float*)d_in[12];
  const float* Wo   = (const float*)d_in[13];
  const float* Wm   = (const float*)d_in[14];
  const float* alo  = (const float*)d_in[15];
  const float* alm  = (const float*)d_in[16];
  const float* A0   = (const float*)d_in[17];
  const float* Ab0  = (const float*)d_in[18];
  const float* A1   = (const float*)d_in[19];
  const float* Ab1  = (const float*)d_in[20];
  const float* A2   = (const float*)d_in[21];
  const float* Ab2  = (const float*)d_in[22];
  const float* C0   = (const float*)d_in[23];
  const float* Cb0  = (const float*)d_in[24];
  const float* C1   = (const float*)d_in[25];
  const float* Cb1  = (const float*)d_in[26];
  const float* C2   = (const float*)d_in[27];
  const float* Cb2  = (const float*)d_in[28];

  float* ws     = (float*)d_ws;        // needs ~41 MiB
  float* x12    = ws + OFF_X12;
  float* hopes  = ws + OFF_HOPES;
  float* hopeG  = ws + OFF_HOPEG;
  float* hmac   = ws + OFF_HMAC;
  float* hmacs  = ws + OFF_HMACS;
  float* ao     = ws + OFF_AO;
  float* am     = ws + OFF_AM;
  float* po     = ws + OFF_PO;
  float* pm     = ws + OFF_PM;
  float* Uo     = ws + OFF_UO;
  float* Um     = ws + OFF_UM;
  float* logits = ws + OFF_LOG;
  int*   flag   = (int*)(ws + OFF_FLAG);
  float* outp   = (float*)d_out;

  probe_mask_kernel<<<1, 256, 0, stream>>>((const unsigned int*)maskp, flag);

  // external attention
  gemm_xt<<<dim3(16, 128), 256, 0, stream>>>(nop, Wtr, btr, x12, 8192, 1024, 128, 128, 128);
  attn_kernel<<<dim3(NH, BB), 256, 0, stream>>>(x12, W0, b0, W1, b1);
  gemm_xt<<<dim3(2, 128), 256, 0, stream>>>(x12, Wp, bp, hopes, 8192, 128, 1024, 1024, 1024);

  // GAT
  gemm_xt<<<dim3(2, 128), 256, 0, stream>>>(nop, Wo, nullptr, hopeG, 8192, 128, 128, 128, 128);
  gemm_xt<<<dim3(2, 8), 256, 0, stream>>>(nmac, Wm, nullptr, hmac, 512, 128, 64, 64, 64);
  rowdot<<<2048, 256, 0, stream>>>(hopeG, alo, ao, 8192);
  rowdot<<<128, 256, 0, stream>>>(hmac, alm, am, 512);
  gat_kernel<<<dim3(NM, BB), 128, 0, stream>>>(adj, ao, am, hopeG, hmac, hmacs);

  // pooling
  pool_kernel<<<16, 512, 0, stream>>>(hopes, po, 512, 1.0f / 512.0f);
  pool_kernel<<<16, 512, 0, stream>>>(hmacs, pm, 32, 1.0f / 32.0f);

  // actor (Uo aliases x12's region — x12 is dead after the proj GEMM above)
  gemm_xt<<<dim3(2, 128), 256, 0, stream>>>(hopes, A0, nullptr, Uo, 8192, 128, 128, 128, 512);
  um_kernel<<<dim3(NM, BB), 128, 0, stream>>>(hmacs, po, pm, A0, Ab0, Um);
  actor_mfma_kernel<<<4096, 256, 0, stream>>>(Uo, Um, A1, Ab1, A2, Ab2, logits);
  final_kernel<<<16, 1024, 0, stream>>>(logits, maskp, aidx, flag, outp);

  // critic
  critic_kernel<<<16, 128, 0, stream>>>(po, pm, C0, Cb0, C1, Cb1, C2, Cb2, outp);
}

// Round 7
// 316.942 us; speedup vs baseline: 2.3949x; 1.5788x over previous
//
#include <hip/hip_runtime.h>

#define BB 16
#define NO 512
#define NM 32
#define DOC 128
#define C8 1024
#define NH 64
#define KD 16

// ---------------- ws layout (float offsets), ~41 MiB total ----------------
#define OFF_X12   0          // [16*512,1024]  x1/x2 of ext-attn (in-place)
#define OFF_UO    0          // [8192,128] (alias: x12 dead by then)
#define OFF_LOG   1048576    // [16,16384] (alias, after Uo)
#define OFF_HOPES 8388608    // [8192,128] ext-attn output
#define OFF_HOPEG 9437184    // [8192,128] GAT h_ope
#define OFF_HMAC  10485760   // [512,128]  GAT h_mac (pre)
#define OFF_HMACS 10551296   // [512,128]  GAT output
#define OFF_AO    10616832   // [8192]
#define OFF_AM    10625024   // [512]
#define OFF_PO    10625536   // [16,128]
#define OFF_PM    10627584   // [16,128]
#define OFF_UM    10629632   // [512,128]  folded U_m + U_p + Ab0
#define OFF_FLAG  10695168   // int flag (mask dtype probe)

using f32x4  = __attribute__((ext_vector_type(4))) float;
using s16x4  = __attribute__((ext_vector_type(4))) short;
using bf16x8 = __attribute__((ext_vector_type(8))) short;   // 8 bf16 (4 VGPRs)

__device__ __forceinline__ float fast_tanh(float x) {
  x = fminf(15.0f, fmaxf(-15.0f, x));
  float e = __expf(2.0f * x);
  return 1.0f - 2.0f * __builtin_amdgcn_rcpf(e + 1.0f);
}

__device__ __forceinline__ short f2bf(float f) {          // RNE f32->bf16
  unsigned u = __builtin_bit_cast(unsigned, f);
  u += 0x7FFFu + ((u >> 16) & 1u);
  return (short)(u >> 16);
}

// ---------------- mask dtype probe ----------------
__global__ void probe_mask_kernel(const unsigned int* __restrict__ mask,
                                  int* __restrict__ flag) {
  __shared__ int s[4];
  int bad = 0;
  for (int i = threadIdx.x; i < 4096; i += 256) {
    unsigned int v = mask[i];
    if (!(v == 0u || v == 1u || v == 0x3f800000u)) bad = 1;
  }
  unsigned long long any = __ballot(bad);
  int lane = threadIdx.x & 63, w = threadIdx.x >> 6;
  if (lane == 0) s[w] = (any != 0ull) ? 1 : 0;
  __syncthreads();
  if (threadIdx.x == 0) flag[0] = s[0] | s[1] | s[2] | s[3];
}

// ---------------- bf16 MFMA GEMM: C[m,n] = sum_k X[m,k]*W[n,k] (+bias[n]) ----------------
// BM=64, BN=128, BK=64. 256 threads = 4 waves, 2x2 wave grid (32 rows x 64 cols each).
// Fragment layouts identical to the verified actor kernel (m89):
//   A: row=lane&15, k=kk*32+(lane>>4)*8..+7 ; B: col=lane&15, same k
//   D: col=lane&15, row=(lane>>4)*4+reg
// LDS stride 80 shorts (160B): 16B-aligned b128 reads, banks spread over all 8 slots.
__global__ __launch_bounds__(256) void gemm_bf16(
    const float* __restrict__ X, const float* __restrict__ W,
    const float* __restrict__ bias, float* __restrict__ C,
    int M, int N, int Kdim, int ldx, int ldw) {
  __shared__ short Xs[64 * 80];
  __shared__ short Ws[128 * 80];
  const int tid = threadIdx.x;
  const int m0 = blockIdx.y * 64, n0 = blockIdx.x * 128;
  const int lane = tid & 63, w = tid >> 6;
  const int wr = w >> 1, wc = w & 1;
  const int rowl = lane & 15, kg = lane >> 4;
  const int sr = tid >> 4, sc = (tid & 15) * 4;   // staging coords
  f32x4 acc[2][4] = {};
  for (int k0 = 0; k0 < Kdim; k0 += 64) {
    __syncthreads();
    #pragma unroll
    for (int rr = 0; rr < 4; ++rr) {
      int r = sr + rr * 16;
      f32x4 v = *(const f32x4*)(X + (m0 + r) * (long)ldx + k0 + sc);
      s16x4 sv;
      sv[0] = f2bf(v[0]); sv[1] = f2bf(v[1]); sv[2] = f2bf(v[2]); sv[3] = f2bf(v[3]);
      *(s16x4*)&Xs[r * 80 + sc] = sv;
    }
    #pragma unroll
    for (int rr = 0; rr < 8; ++rr) {
      int r = sr + rr * 16;
      f32x4 v = *(const f32x4*)(W + (n0 + r) * (long)ldw + k0 + sc);
      s16x4 sv;
      sv[0] = f2bf(v[0]); sv[1] = f2bf(v[1]); sv[2] = f2bf(v[2]); sv[3] = f2bf(v[3]);
      *(s16x4*)&Ws[r * 80 + sc] = sv;
    }
    __syncthreads();
    #pragma unroll
    for (int kk = 0; kk < 2; ++kk) {
      bf16x8 a[2], bfr[4];
      #pragma unroll
      for (int mi = 0; mi < 2; ++mi)
        a[mi] = *(const bf16x8*)&Xs[(wr * 32 + mi * 16 + rowl) * 80 + kk * 32 + kg * 8];
      #pragma unroll
      for (int ni = 0; ni < 4; ++ni)
        bfr[ni] = *(const bf16x8*)&Ws[(wc * 64 + ni * 16 + rowl) * 80 + kk * 32 + kg * 8];
      #pragma unroll
      for (int mi = 0; mi < 2; ++mi)
        #pragma unroll
        for (int ni = 0; ni < 4; ++ni)
          acc[mi][ni] = __builtin_amdgcn_mfma_f32_16x16x32_bf16(a[mi], bfr[ni], acc[mi][ni], 0, 0, 0);
    }
  }
  #pragma unroll
  for (int mi = 0; mi < 2; ++mi) {
    #pragma unroll
    for (int ni = 0; ni < 4; ++ni) {
      int col = n0 + wc * 64 + ni * 16 + rowl;
      float bv = bias ? bias[col] : 0.0f;
      int rb = m0 + wr * 32 + mi * 16 + kg * 4;
      #pragma unroll
      for (int r = 0; r < 4; ++r)
        C[(rb + r) * (long)N + col] = acc[mi][ni][r] + bv;
    }
  }
}

// ---------------- generic f32 GEMM (kept for the small hmac GEMM) ----------------
__global__ __launch_bounds__(256) void gemm_xt(
    const float* __restrict__ X, const float* __restrict__ W,
    const float* __restrict__ bias, float* __restrict__ C,
    int M, int N, int Kdim, int ldx, int ldw) {
  __shared__ float Xs[64][33];
  __shared__ float Ws[64][33];
  const int tid = threadIdx.x;
  const int tx = tid & 15, ty = tid >> 4;
  const int m0 = blockIdx.y * 64, n0 = blockIdx.x * 64;
  float acc[4][4] = {};
  for (int k0 = 0; k0 < Kdim; k0 += 32) {
    #pragma unroll
    for (int l = 0; l < 8; ++l) {
      int f = l * 256 + tid;
      int r = f >> 5, c = f & 31;
      Xs[r][c] = X[(m0 + r) * ldx + k0 + c];
      Ws[r][c] = W[(n0 + r) * ldw + k0 + c];
    }
    __syncthreads();
    #pragma unroll 8
    for (int kk = 0; kk < 32; ++kk) {
      float xr[4], wr[4];
      #pragma unroll
      for (int i = 0; i < 4; ++i) xr[i] = Xs[ty * 4 + i][kk];
      #pragma unroll
      for (int j = 0; j < 4; ++j) wr[j] = Ws[tx * 4 + j][kk];
      #pragma unroll
      for (int i = 0; i < 4; ++i)
        #pragma unroll
        for (int j = 0; j < 4; ++j)
          acc[i][j] = fmaf(xr[i], wr[j], acc[i][j]);
    }
    __syncthreads();
  }
  #pragma unroll
  for (int i = 0; i < 4; ++i) {
    int m = m0 + ty * 4 + i;
    #pragma unroll
    for (int j = 0; j < 4; ++j) {
      int n = n0 + tx * 4 + j;
      C[m * N + n] = acc[i][j] + (bias ? bias[n] : 0.0f);
    }
  }
}

// ---------------- external attention middle: per (b,h) slice, in place on x12 ----------------
__global__ __launch_bounds__(256) void attn_kernel(
    float* __restrict__ x12,
    const float* __restrict__ W0, const float* __restrict__ b0,
    const float* __restrict__ W1, const float* __restrict__ b1) {
  __shared__ float S[NO][KD + 1];
  __shared__ float red[16][17];
  __shared__ float colmax[16], colsum[16];
  __shared__ float rs[NO];
  const int b = blockIdx.y, h = blockIdx.x;
  const int tid = threadIdx.x;
  const int tk = tid & 15, tg = tid >> 4;
  float* base = x12 + (b * NO) * C8 + h * KD;
  #pragma unroll
  for (int l = 0; l < 32; ++l) {
    int f = l * 256 + tid;
    int n = f >> 4, k = f & 15;
    S[n][k] = base[n * C8 + k];
  }
  __syncthreads();
  float w0r[16];
  #pragma unroll
  for (int k = 0; k < 16; ++k) w0r[k] = W0[tk * 16 + k];
  const float b0v = b0[tk];
  float Areg[32];
  for (int i = 0; i < 32; ++i) {
    int n = tg + 16 * i;
    float acc = b0v;
    #pragma unroll
    for (int k = 0; k < 16; ++k) acc = fmaf(S[n][k], w0r[k], acc);
    Areg[i] = acc;
  }
  __syncthreads();
  for (int i = 0; i < 32; ++i) { int n = tg + 16 * i; S[n][tk] = Areg[i]; }
  __syncthreads();
  float mx = -1e30f;
  for (int i = 0; i < 32; ++i) mx = fmaxf(mx, Areg[i]);
  red[tg][tk] = mx;
  __syncthreads();
  if (tg == 0) {
    float mm = red[0][tk];
    for (int g = 1; g < 16; ++g) mm = fmaxf(mm, red[g][tk]);
    colmax[tk] = mm;
  }
  __syncthreads();
  const float cm = colmax[tk];
  float s = 0.f;
  for (int i = 0; i < 32; ++i) { float e = __expf(Areg[i] - cm); Areg[i] = e; s += e; }
  __syncthreads();
  red[tg][tk] = s;
  __syncthreads();
  if (tg == 0) {
    float ss = 0.f;
    for (int g = 0; g < 16; ++g) ss += red[g][tk];
    colsum[tk] = ss;
  }
  __syncthreads();
  const float inv = 1.0f / colsum[tk];
  for (int i = 0; i < 32; ++i) { int n = tg + 16 * i; S[n][tk] = Areg[i] * inv; }
  __syncthreads();
  #pragma unroll
  for (int rr = 0; rr < 2; ++rr) {
    int n = tid * 2 + rr;
    float t = 0.f;
    #pragma unroll
    for (int k = 0; k < 16; ++k) t += S[n][k];
    rs[n] = t;
  }
  __syncthreads();
  float w1r[16];
  #pragma unroll
  for (int k = 0; k < 16; ++k) w1r[k] = W1[tk * 16 + k];
  const float b1v = b1[tk];
  for (int i = 0; i < 32; ++i) {
    int n = tg + 16 * i;
    float rinv = 1.0f / (1e-10f + rs[n]);
    float acc = b1v;
    #pragma unroll
    for (int k = 0; k < 16; ++k) acc = fmaf(S[n][k] * rinv, w1r[k], acc);
    base[n * C8 + tk] = acc;
  }
}

// ---------------- row dot with alpha (a_o / a_m) ----------------
__global__ void rowdot(const float* __restrict__ X, const float* __restrict__ alpha,
                       float* __restrict__ out, int R) {
  int wid = (blockIdx.x * blockDim.x + threadIdx.x) >> 6;
  int lane = threadIdx.x & 63;
  if (wid >= R) return;
  const float* row = X + wid * 128;
  float v = fmaf(row[lane], alpha[lane], row[lane + 64] * alpha[lane + 64]);
  #pragma unroll
  for (int off = 32; off; off >>= 1) v += __shfl_down(v, off);
  if (lane == 0) out[wid] = v;
}

// ---------------- GAT per (b,m) ----------------
__global__ __launch_bounds__(128) void gat_kernel(
    const float* __restrict__ adj, const float* __restrict__ ao,
    const float* __restrict__ am, const float* __restrict__ hopeG,
    const float* __restrict__ hmac, float* __restrict__ hmacs) {
  __shared__ float al[NO];
  __shared__ float sc[2];
  const int b = blockIdx.y, m = blockIdx.x;
  const int tid = threadIdx.x;
  const int lane = tid & 63, w = tid >> 6;
  const float amv = am[b * NM + m];
  float ev[4], adjv[4];
  float mx = -1e30f;
  #pragma unroll
  for (int i = 0; i < 4; ++i) {
    int o = tid + i * 128;
    float a = adj[(b * NO + o) * NM + m];
    adjv[i] = a;
    float e = ao[b * NO + o] + amv;
    e = (e >= 0.f) ? e : 0.2f * e;
    ev[i] = e;
    if (a == 1.0f) mx = fmaxf(mx, e);
  }
  #pragma unroll
  for (int off = 32; off; off >>= 1) mx = fmaxf(mx, __shfl_down(mx, off));
  if (lane == 0) sc[w] = mx;
  __syncthreads();
  mx = fmaxf(sc[0], sc[1]);
  float s = 0.f;
  float pv[4];
  #pragma unroll
  for (int i = 0; i < 4; ++i) {
    float p = (adjv[i] == 1.0f) ? __expf(ev[i] - mx) : 0.f;
    pv[i] = p; s += p;
  }
  #pragma unroll
  for (int off = 32; off; off >>= 1) s += __shfl_down(s, off);
  __syncthreads();
  if (lane == 0) sc[w] = s;
  __syncthreads();
  s = sc[0] + sc[1];
  const float sinv = (s > 0.f) ? 1.0f / s : 0.f;
  #pragma unroll
  for (int i = 0; i < 4; ++i) al[tid + i * 128] = pv[i] * sinv;
  __syncthreads();
  float acc = 0.f;
  for (int o = 0; o < NO; ++o) acc = fmaf(al[o], hopeG[(b * NO + o) * DOC + tid], acc);
  hmacs[(b * NM + m) * DOC + tid] = acc + hmac[(b * NM + m) * DOC + tid];
}

// ---------------- mean-pool over rows (512 threads: 4-way row split) ----------------
__global__ __launch_bounds__(512) void pool_kernel(const float* __restrict__ X,
                                                   float* __restrict__ out,
                                                   int R, float inv) {
  __shared__ float part[4][128];
  const int b = blockIdx.x;
  const int d = threadIdx.x & 127, g = threadIdx.x >> 7;
  const int per = R >> 2;
  float acc = 0.f;
  for (int r = g * per; r < (g + 1) * per; ++r) acc += X[(b * R + r) * 128 + d];
  part[g][d] = acc;
  __syncthreads();
  if (g == 0)
    out[b * 128 + d] = (part[0][d] + part[1][d] + part[2][d] + part[3][d]) * inv;
}

// ---------------- folded U_m ----------------
__global__ __launch_bounds__(128) void um_kernel(
    const float* __restrict__ hmacs, const float* __restrict__ po,
    const float* __restrict__ pm, const float* __restrict__ A0,
    const float* __restrict__ Ab0, float* __restrict__ um) {
  __shared__ float v[384];
  const int b = blockIdx.y, m = blockIdx.x;
  const int j = threadIdx.x;
  v[j] = hmacs[(b * NM + m) * 128 + j];
  v[128 + j] = po[b * 128 + j];
  v[256 + j] = pm[b * 128 + j];
  __syncthreads();
  const float* a = A0 + j * 512 + 128;
  float acc = Ab0[j];
  for (int k = 0; k < 384; ++k) acc = fmaf(a[k], v[k], acc);
  um[(b * NM + m) * 128 + j] = acc;
}

// ---------------- actor via bf16 MFMA 16x16x32 (verified r6: absmax 0.0) ----------------
__global__ __launch_bounds__(256) void actor_mfma_kernel(
    const float* __restrict__ Uo, const float* __restrict__ Um,
    const float* __restrict__ A1, const float* __restrict__ Ab1,
    const float* __restrict__ A2, const float* __restrict__ Ab2,
    float* __restrict__ logits) {
  __shared__ short a1s[128 * 136];
  __shared__ float umv[128];
  const int tid = threadIdx.x;
  const int rbase = blockIdx.x * 64;       // flat row = b*16384 + m*512 + o
  const int b = rbase >> 14;
  const int m = (rbase & 16383) >> 9;
  #pragma unroll
  for (int it = 0; it < 16; ++it) {
    int f = it * 1024 + tid * 4;
    int c = f >> 7, k = f & 127;
    f32x4 v = *(const f32x4*)(A1 + c * 128 + k);
    s16x4 sv;
    sv[0] = f2bf(v[0]); sv[1] = f2bf(v[1]); sv[2] = f2bf(v[2]); sv[3] = f2bf(v[3]);
    *(s16x4*)&a1s[c * 136 + k] = sv;
  }
  if (tid < 128) umv[tid] = Um[(b * NM + m) * 128 + tid];
  __syncthreads();

  const int lane = tid & 63, w = tid >> 6;
  const int rowl = lane & 15, kg = lane >> 4;
  const float* uo = Uo + (rbase + w * 16 + rowl) * 128;
  bf16x8 af[4];
  #pragma unroll
  for (int kk = 0; kk < 4; ++kk) {
    int kb = kk * 32 + kg * 8;
    f32x4 u0 = *(const f32x4*)(uo + kb);
    f32x4 u1 = *(const f32x4*)(uo + kb + 4);
    #pragma unroll
    for (int e = 0; e < 4; ++e) af[kk][e]     = f2bf(fast_tanh(u0[e] + umv[kb + e]));
    #pragma unroll
    for (int e = 0; e < 4; ++e) af[kk][4 + e] = f2bf(fast_tanh(u1[e] + umv[kb + 4 + e]));
  }
  float partrow[4] = {0.f, 0.f, 0.f, 0.f};
  #pragma unroll
  for (int ct = 0; ct < 8; ++ct) {
    f32x4 acc = {0.f, 0.f, 0.f, 0.f};
    #pragma unroll
    for (int kk = 0; kk < 4; ++kk) {
      bf16x8 bf = *(const bf16x8*)&a1s[(ct * 16 + rowl) * 136 + kk * 32 + kg * 8];
      acc = __builtin_amdgcn_mfma_f32_16x16x32_bf16(af[kk], bf, acc, 0, 0, 0);
    }
    const int col = ct * 16 + rowl;
    const float ab = Ab1[col], a2c = A2[col];
    #pragma unroll
    for (int r = 0; r < 4; ++r) {
      float z2 = fast_tanh(acc[r] + ab);
      partrow[r] = fmaf(a2c, z2, partrow[r]);
    }
  }
  const float ab2 = Ab2[0];
  #pragma unroll
  for (int r = 0; r < 4; ++r) {
    float v = partrow[r];
    #pragma unroll
    for (int off = 1; off < 16; off <<= 1) v += __shfl_xor(v, off);
    if (rowl == 0) logits[rbase + w * 16 + kg * 4 + r] = v + ab2;
  }
}

// ---------------- masked log-softmax + gather + entropy (1024 threads) ----------------
__global__ __launch_bounds__(1024) void final_kernel(
    const float* __restrict__ logits, const void* __restrict__ maskp,
    const int* __restrict__ aidx, const int* __restrict__ flag,
    float* __restrict__ out) {
  __shared__ float sc[16], sc2[16];
  const int b = blockIdx.x;
  const int tid = threadIdx.x;
  const int lane = tid & 63, w = tid >> 6;
  const bool word_mode = (flag[0] == 0);
  const unsigned int* mw = (const unsigned int*)maskp;
  const unsigned char* mb = (const unsigned char*)maskp;
  const float* lg = logits + b * (NM * NO);
  float mx = -1e30f;
  for (int s = 0; s < 16; ++s) {
    int i = s * 1024 + tid;
    int o = i & 511, mm = i >> 9;
    int mofs = (b * NO + o) * NM + mm;
    bool msk = word_mode ? (mw[mofs] != 0u) : (mb[mofs] != 0);
    if (msk) mx = fmaxf(mx, lg[i]);
  }
  #pragma unroll
  for (int off = 32; off; off >>= 1) mx = fmaxf(mx, __shfl_down(mx, off));
  if (lane == 0) sc[w] = mx;
  __syncthreads();
  if (tid == 0) {
    float m2 = sc[0];
    for (int k = 1; k < 16; ++k) m2 = fmaxf(m2, sc[k]);
    sc[0] = m2;
  }
  __syncthreads();
  mx = sc[0];
  __syncthreads();
  float S = 0.f, T = 0.f;
  for (int s = 0; s < 16; ++s) {
    int i = s * 1024 + tid;
    int o = i & 511, mm = i >> 9;
    int mofs = (b * NO + o) * NM + mm;
    bool msk = word_mode ? (mw[mofs] != 0u) : (mb[mofs] != 0);
    if (msk) {
      float d = lg[i] - mx;
      float e = __expf(d);
      S += e;
      T = fmaf(e, d, T);
    }
  }
  #pragma unroll
  for (int off = 32; off; off >>= 1) { S += __shfl_down(S, off); T += __shfl_down(T, off); }
  if (lane == 0) { sc[w] = S; sc2[w] = T; }
  __syncthreads();
  if (tid == 0) {
    float St = 0.f, Tt = 0.f;
    for (int k = 0; k < 16; ++k) { St += sc[k]; Tt += sc2[k]; }
    float lS = logf(St);
    out[b] = lg[aidx[b]] - mx - lS;          // action_logprobs
    out[32 + b] = lS - Tt / St;              // dist_entropys
  }
}

// ---------------- critic MLP (per batch) ----------------
__global__ __launch_bounds__(128) void critic_kernel(
    const float* __restrict__ po, const float* __restrict__ pm,
    const float* __restrict__ C0, const float* __restrict__ Cb0,
    const float* __restrict__ C1, const float* __restrict__ Cb1,
    const float* __restrict__ C2, const float* __restrict__ Cb2,
    float* __restrict__ out) {
  __shared__ float v[256];
  __shared__ float z[128];
  __shared__ float sc[2];
  const int b = blockIdx.x;
  const int j = threadIdx.x;
  v[j] = po[b * 128 + j];
  v[128 + j] = pm[b * 128 + j];
  __syncthreads();
  float acc = Cb0[j];
  for (int k = 0; k < 256; ++k) acc = fmaf(C0[j * 256 + k], v[k], acc);
  z[j] = fast_tanh(acc);
  __syncthreads();
  acc = Cb1[j];
  for (int k = 0; k < 128; ++k) acc = fmaf(C1[j * 128 + k], z[k], acc);
  float z2 = fast_tanh(acc);
  float p = C2[j] * z2;
  #pragma unroll
  for (int off = 32; off; off >>= 1) p += __shfl_down(p, off);
  const int lane = j & 63, w = j >> 6;
  if (lane == 0) sc[w] = p;
  __syncthreads();
  if (j == 0) out[16 + b] = sc[0] + sc[1] + Cb2[0];   // state_values
}

extern "C" void kernel_launch(void* const* d_in, const int* in_sizes, int n_in,
                              void* d_out, int out_size, void* d_ws, size_t ws_size,
                              hipStream_t stream) {
  (void)in_sizes; (void)n_in; (void)out_size; (void)ws_size;
  const float* adj  = (const float*)d_in[0];
  const float* nop  = (const float*)d_in[1];
  const float* nmac = (const float*)d_in[2];
  const void*  maskp = d_in[3];
  const int*   aidx = (const int*)d_in[4];
  const float* Wtr  = (const float*)d_in[5];
  const float* btr  = (const float*)d_in[6];
  const float* W0   = (const float*)d_in[7];
  const float* b0   = (const float*)d_in[8];
  const float* W1   = (const float*)d_in[9];
  const float* b1   = (const float*)d_in[10];
  const float* Wp   = (const float*)d_in[11];
  const float* bp   = (const float*)d_in[12];
  const float* Wo   = (const float*)d_in[13];
  const float* Wm   = (const float*)d_in[14];
  const float* alo  = (const float*)d_in[15];
  const float* alm  = (const float*)d_in[16];
  const float* A0   = (const float*)d_in[17];
  const float* Ab0  = (const float*)d_in[18];
  const float* A1   = (const float*)d_in[19];
  const float* Ab1  = (const float*)d_in[20];
  const float* A2   = (const float*)d_in[21];
  const float* Ab2  = (const float*)d_in[22];
  const float* C0   = (const float*)d_in[23];
  const float* Cb0  = (const float*)d_in[24];
  const float* C1   = (const float*)d_in[25];
  const float* Cb1  = (const float*)d_in[26];
  const float* C2   = (const float*)d_in[27];
  const float* Cb2  = (const float*)d_in[28];

  float* ws     = (float*)d_ws;        // needs ~41 MiB
  float* x12    = ws + OFF_X12;
  float* hopes  = ws + OFF_HOPES;
  float* hopeG  = ws + OFF_HOPEG;
  float* hmac   = ws + OFF_HMAC;
  float* hmacs  = ws + OFF_HMACS;
  float* ao     = ws + OFF_AO;
  float* am     = ws + OFF_AM;
  float* po     = ws + OFF_PO;
  float* pm     = ws + OFF_PM;
  float* Uo     = ws + OFF_UO;
  float* Um     = ws + OFF_UM;
  float* logits = ws + OFF_LOG;
  int*   flag   = (int*)(ws + OFF_FLAG);
  float* outp   = (float*)d_out;

  probe_mask_kernel<<<1, 256, 0, stream>>>((const unsigned int*)maskp, flag);

  // external attention
  gemm_bf16<<<dim3(8, 128), 256, 0, stream>>>(nop, Wtr, btr, x12, 8192, 1024, 128, 128, 128);
  attn_kernel<<<dim3(NH, BB), 256, 0, stream>>>(x12, W0, b0, W1, b1);
  gemm_bf16<<<dim3(1, 128), 256, 0, stream>>>(x12, Wp, bp, hopes, 8192, 128, 1024, 1024, 1024);

  // GAT
  gemm_bf16<<<dim3(1, 128), 256, 0, stream>>>(nop, Wo, nullptr, hopeG, 8192, 128, 128, 128, 128);
  gemm_xt<<<dim3(2, 8), 256, 0, stream>>>(nmac, Wm, nullptr, hmac, 512, 128, 64, 64, 64);
  rowdot<<<2048, 256, 0, stream>>>(hopeG, alo, ao, 8192);
  rowdot<<<128, 256, 0, stream>>>(hmac, alm, am, 512);
  gat_kernel<<<dim3(NM, BB), 128, 0, stream>>>(adj, ao, am, hopeG, hmac, hmacs);

  // pooling
  pool_kernel<<<16, 512, 0, stream>>>(hopes, po, 512, 1.0f / 512.0f);
  pool_kernel<<<16, 512, 0, stream>>>(hmacs, pm, 32, 1.0f / 32.0f);

  // actor (Uo aliases x12's region — x12 is dead after the proj GEMM above)
  gemm_bf16<<<dim3(1, 128), 256, 0, stream>>>(hopes, A0, nullptr, Uo, 8192, 128, 128, 128, 512);
  um_kernel<<<dim3(NM, BB), 128, 0, stream>>>(hmacs, po, pm, A0, Ab0, Um);
  actor_mfma_kernel<<<4096, 256, 0, stream>>>(Uo, Um, A1, Ab1, A2, Ab2, logits);
  final_kernel<<<16, 1024, 0, stream>>>(logits, maskp, aidx, flag, outp);

  // critic
  critic_kernel<<<16, 128, 0, stream>>>(po, pm, C0, Cb0, C1, Cb1, C2, Cb2, outp);
}

// Round 8
// 292.210 us; speedup vs baseline: 2.5976x; 1.0846x over previous
//
#include <hip/hip_runtime.h>

#define BB 16
#define NO 512
#define NM 32
#define DOC 128
#define C8 1024
#define NH 64
#define KD 16

// ---------------- ws layout (float offsets), ~41 MiB total ----------------
#define OFF_X12   0          // [16*512,1024]  x1/x2 of ext-attn (in-place)
#define OFF_UO    0          // [8192,128] (alias: x12 dead by then)
#define OFF_LOG   1048576    // [16,16384] (alias, after Uo)
#define OFF_HOPES 8388608    // [8192,128] ext-attn output
#define OFF_HOPEG 9437184    // [8192,128] GAT h_ope
#define OFF_HMAC  10485760   // [512,128]  GAT h_mac (pre)
#define OFF_HMACS 10551296   // [512,128]  GAT output
#define OFF_AO    10616832   // [8192]
#define OFF_AM    10625024   // [512]
#define OFF_PO    10625536   // [16,128]
#define OFF_PM    10627584   // [16,128]
#define OFF_UM    10629632   // [512,128]  folded U_m + U_p + Ab0
#define OFF_FLAG  10695168   // int flag (mask dtype probe)

using f32x4  = __attribute__((ext_vector_type(4))) float;
using s16x4  = __attribute__((ext_vector_type(4))) short;
using bf16x8 = __attribute__((ext_vector_type(8))) short;   // 8 bf16 (4 VGPRs)

__device__ __forceinline__ float fast_tanh(float x) {
  x = fminf(15.0f, fmaxf(-15.0f, x));
  float e = __expf(2.0f * x);
  return 1.0f - 2.0f * __builtin_amdgcn_rcpf(e + 1.0f);
}

__device__ __forceinline__ short f2bf(float f) {          // RNE f32->bf16
  unsigned u = __builtin_bit_cast(unsigned, f);
  u += 0x7FFFu + ((u >> 16) & 1u);
  return (short)(u >> 16);
}

__device__ __forceinline__ bf16x8 pack8(f32x4 u0, f32x4 u1) {
  bf16x8 r;
  #pragma unroll
  for (int e = 0; e < 4; ++e) { r[e] = f2bf(u0[e]); r[4 + e] = f2bf(u1[e]); }
  return r;
}

// ---------------- mask dtype probe ----------------
__global__ void probe_mask_kernel(const unsigned int* __restrict__ mask,
                                  int* __restrict__ flag) {
  __shared__ int s[4];
  int bad = 0;
  for (int i = threadIdx.x; i < 4096; i += 256) {
    unsigned int v = mask[i];
    if (!(v == 0u || v == 1u || v == 0x3f800000u)) bad = 1;
  }
  unsigned long long any = __ballot(bad);
  int lane = threadIdx.x & 63, w = threadIdx.x >> 6;
  if (lane == 0) s[w] = (any != 0ull) ? 1 : 0;
  __syncthreads();
  if (threadIdx.x == 0) flag[0] = s[0] | s[1] | s[2] | s[3];
}

// ---------------- per-wave no-LDS bf16 MFMA GEMM ----------------
// C[m,n] = sum_k X[m,k]*W[n,k] (+bias[n]).  Per-wave tile (MT*16) x 64.
// No LDS, no barriers: fragments loaded directly from global (actor-kernel
// layouts, verified r6): A row=lane&15, k=(lane>>4)*8+e; B col=lane&15;
// D col=lane&15, row=(lane>>4)*4+reg. Register double-buffer k-pipeline.
// Requires Kdim % 64 == 0.
template<int MT>
__device__ __forceinline__ void loadk(const float* xb, const float* wb,
                                      long sx, long sw, int k0,
                                      f32x4 (&xa)[MT][2], f32x4 (&wa)[4][2]) {
  #pragma unroll
  for (int mi = 0; mi < MT; ++mi) {
    xa[mi][0] = *(const f32x4*)(xb + mi * sx + k0);
    xa[mi][1] = *(const f32x4*)(xb + mi * sx + k0 + 4);
  }
  #pragma unroll
  for (int ni = 0; ni < 4; ++ni) {
    wa[ni][0] = *(const f32x4*)(wb + ni * sw + k0);
    wa[ni][1] = *(const f32x4*)(wb + ni * sw + k0 + 4);
  }
}

template<int MT>
__device__ __forceinline__ void consume(f32x4 (&xa)[MT][2], f32x4 (&wa)[4][2],
                                        f32x4 (&acc)[MT][4]) {
  bf16x8 bfr[4];
  #pragma unroll
  for (int ni = 0; ni < 4; ++ni) bfr[ni] = pack8(wa[ni][0], wa[ni][1]);
  #pragma unroll
  for (int mi = 0; mi < MT; ++mi) {
    bf16x8 af = pack8(xa[mi][0], xa[mi][1]);
    #pragma unroll
    for (int ni = 0; ni < 4; ++ni)
      acc[mi][ni] = __builtin_amdgcn_mfma_f32_16x16x32_bf16(af, bfr[ni], acc[mi][ni], 0, 0, 0);
  }
}

template<int MT>
__global__ __launch_bounds__(256) void gemm_wave(
    const float* __restrict__ X, const float* __restrict__ W,
    const float* __restrict__ bias, float* __restrict__ C,
    int N, int Kdim, int ldx, int ldw) {
  const int tid = threadIdx.x;
  const int lane = tid & 63, w = tid >> 6;
  const int rowl = lane & 15, kg = lane >> 4;
  const int n0 = blockIdx.x * 64;
  const int m0 = (blockIdx.y * 4 + w) * (MT * 16);
  const float* xb = X + (long)(m0 + rowl) * ldx + kg * 8;
  const float* wb = W + (long)(n0 + rowl) * ldw + kg * 8;
  const long sx = (long)16 * ldx, sw = (long)16 * ldw;
  f32x4 acc[MT][4] = {};
  f32x4 A0[MT][2], B0[4][2], A1[MT][2], B1[4][2];
  loadk<MT>(xb, wb, sx, sw, 0, A0, B0);
  for (int k = 0; k < Kdim; k += 64) {
    loadk<MT>(xb, wb, sx, sw, k + 32, A1, B1);
    consume<MT>(A0, B0, acc);
    if (k + 64 < Kdim) loadk<MT>(xb, wb, sx, sw, k + 64, A0, B0);
    consume<MT>(A1, B1, acc);
  }
  #pragma unroll
  for (int mi = 0; mi < MT; ++mi) {
    #pragma unroll
    for (int ni = 0; ni < 4; ++ni) {
      int col = n0 + ni * 16 + rowl;
      float bv = bias ? bias[col] : 0.0f;
      int rb = m0 + mi * 16 + kg * 4;
      #pragma unroll
      for (int r = 0; r < 4; ++r)
        C[(long)(rb + r) * N + col] = acc[mi][ni][r] + bv;
    }
  }
}

// ---------------- generic f32 GEMM (kept for the small hmac GEMM) ----------------
__global__ __launch_bounds__(256) void gemm_xt(
    const float* __restrict__ X, const float* __restrict__ W,
    const float* __restrict__ bias, float* __restrict__ C,
    int M, int N, int Kdim, int ldx, int ldw) {
  __shared__ float Xs[64][33];
  __shared__ float Ws[64][33];
  const int tid = threadIdx.x;
  const int tx = tid & 15, ty = tid >> 4;
  const int m0 = blockIdx.y * 64, n0 = blockIdx.x * 64;
  float acc[4][4] = {};
  for (int k0 = 0; k0 < Kdim; k0 += 32) {
    #pragma unroll
    for (int l = 0; l < 8; ++l) {
      int f = l * 256 + tid;
      int r = f >> 5, c = f & 31;
      Xs[r][c] = X[(m0 + r) * ldx + k0 + c];
      Ws[r][c] = W[(n0 + r) * ldw + k0 + c];
    }
    __syncthreads();
    #pragma unroll 8
    for (int kk = 0; kk < 32; ++kk) {
      float xr[4], wr[4];
      #pragma unroll
      for (int i = 0; i < 4; ++i) xr[i] = Xs[ty * 4 + i][kk];
      #pragma unroll
      for (int j = 0; j < 4; ++j) wr[j] = Ws[tx * 4 + j][kk];
      #pragma unroll
      for (int i = 0; i < 4; ++i)
        #pragma unroll
        for (int j = 0; j < 4; ++j)
          acc[i][j] = fmaf(xr[i], wr[j], acc[i][j]);
    }
    __syncthreads();
  }
  #pragma unroll
  for (int i = 0; i < 4; ++i) {
    int m = m0 + ty * 4 + i;
    #pragma unroll
    for (int j = 0; j < 4; ++j) {
      int n = n0 + tx * 4 + j;
      C[m * N + n] = acc[i][j] + (bias ? bias[n] : 0.0f);
    }
  }
}

// ---------------- external attention middle: per (b,h) slice, in place on x12 ----------------
__global__ __launch_bounds__(256) void attn_kernel(
    float* __restrict__ x12,
    const float* __restrict__ W0, const float* __restrict__ b0,
    const float* __restrict__ W1, const float* __restrict__ b1) {
  __shared__ float S[NO][KD + 1];
  __shared__ float red[16][17];
  __shared__ float colmax[16], colsum[16];
  __shared__ float rs[NO];
  const int b = blockIdx.y, h = blockIdx.x;
  const int tid = threadIdx.x;
  const int tk = tid & 15, tg = tid >> 4;
  float* base = x12 + (b * NO) * C8 + h * KD;
  #pragma unroll
  for (int l = 0; l < 32; ++l) {
    int f = l * 256 + tid;
    int n = f >> 4, k = f & 15;
    S[n][k] = base[n * C8 + k];
  }
  __syncthreads();
  float w0r[16];
  #pragma unroll
  for (int k = 0; k < 16; ++k) w0r[k] = W0[tk * 16 + k];
  const float b0v = b0[tk];
  float Areg[32];
  for (int i = 0; i < 32; ++i) {
    int n = tg + 16 * i;
    float acc = b0v;
    #pragma unroll
    for (int k = 0; k < 16; ++k) acc = fmaf(S[n][k], w0r[k], acc);
    Areg[i] = acc;
  }
  __syncthreads();
  for (int i = 0; i < 32; ++i) { int n = tg + 16 * i; S[n][tk] = Areg[i]; }
  __syncthreads();
  float mx = -1e30f;
  for (int i = 0; i < 32; ++i) mx = fmaxf(mx, Areg[i]);
  red[tg][tk] = mx;
  __syncthreads();
  if (tg == 0) {
    float mm = red[0][tk];
    for (int g = 1; g < 16; ++g) mm = fmaxf(mm, red[g][tk]);
    colmax[tk] = mm;
  }
  __syncthreads();
  const float cm = colmax[tk];
  float s = 0.f;
  for (int i = 0; i < 32; ++i) { float e = __expf(Areg[i] - cm); Areg[i] = e; s += e; }
  __syncthreads();
  red[tg][tk] = s;
  __syncthreads();
  if (tg == 0) {
    float ss = 0.f;
    for (int g = 0; g < 16; ++g) ss += red[g][tk];
    colsum[tk] = ss;
  }
  __syncthreads();
  const float inv = 1.0f / colsum[tk];
  for (int i = 0; i < 32; ++i) { int n = tg + 16 * i; S[n][tk] = Areg[i] * inv; }
  __syncthreads();
  #pragma unroll
  for (int rr = 0; rr < 2; ++rr) {
    int n = tid * 2 + rr;
    float t = 0.f;
    #pragma unroll
    for (int k = 0; k < 16; ++k) t += S[n][k];
    rs[n] = t;
  }
  __syncthreads();
  float w1r[16];
  #pragma unroll
  for (int k = 0; k < 16; ++k) w1r[k] = W1[tk * 16 + k];
  const float b1v = b1[tk];
  for (int i = 0; i < 32; ++i) {
    int n = tg + 16 * i;
    float rinv = 1.0f / (1e-10f + rs[n]);
    float acc = b1v;
    #pragma unroll
    for (int k = 0; k < 16; ++k) acc = fmaf(S[n][k] * rinv, w1r[k], acc);
    base[n * C8 + tk] = acc;
  }
}

// ---------------- row dot with alpha (a_o / a_m) ----------------
__global__ void rowdot(const float* __restrict__ X, const float* __restrict__ alpha,
                       float* __restrict__ out, int R) {
  int wid = (blockIdx.x * blockDim.x + threadIdx.x) >> 6;
  int lane = threadIdx.x & 63;
  if (wid >= R) return;
  const float* row = X + wid * 128;
  float v = fmaf(row[lane], alpha[lane], row[lane + 64] * alpha[lane + 64]);
  #pragma unroll
  for (int off = 32; off; off >>= 1) v += __shfl_down(v, off);
  if (lane == 0) out[wid] = v;
}

// ---------------- GAT per (b,m) ----------------
__global__ __launch_bounds__(128) void gat_kernel(
    const float* __restrict__ adj, const float* __restrict__ ao,
    const float* __restrict__ am, const float* __restrict__ hopeG,
    const float* __restrict__ hmac, float* __restrict__ hmacs) {
  __shared__ float al[NO];
  __shared__ float sc[2];
  const int b = blockIdx.y, m = blockIdx.x;
  const int tid = threadIdx.x;
  const int lane = tid & 63, w = tid >> 6;
  const float amv = am[b * NM + m];
  float ev[4], adjv[4];
  float mx = -1e30f;
  #pragma unroll
  for (int i = 0; i < 4; ++i) {
    int o = tid + i * 128;
    float a = adj[(b * NO + o) * NM + m];
    adjv[i] = a;
    float e = ao[b * NO + o] + amv;
    e = (e >= 0.f) ? e : 0.2f * e;
    ev[i] = e;
    if (a == 1.0f) mx = fmaxf(mx, e);
  }
  #pragma unroll
  for (int off = 32; off; off >>= 1) mx = fmaxf(mx, __shfl_down(mx, off));
  if (lane == 0) sc[w] = mx;
  __syncthreads();
  mx = fmaxf(sc[0], sc[1]);
  float s = 0.f;
  float pv[4];
  #pragma unroll
  for (int i = 0; i < 4; ++i) {
    float p = (adjv[i] == 1.0f) ? __expf(ev[i] - mx) : 0.f;
    pv[i] = p; s += p;
  }
  #pragma unroll
  for (int off = 32; off; off >>= 1) s += __shfl_down(s, off);
  __syncthreads();
  if (lane == 0) sc[w] = s;
  __syncthreads();
  s = sc[0] + sc[1];
  const float sinv = (s > 0.f) ? 1.0f / s : 0.f;
  #pragma unroll
  for (int i = 0; i < 4; ++i) al[tid + i * 128] = pv[i] * sinv;
  __syncthreads();
  float acc = 0.f;
  for (int o = 0; o < NO; ++o) acc = fmaf(al[o], hopeG[(b * NO + o) * DOC + tid], acc);
  hmacs[(b * NM + m) * DOC + tid] = acc + hmac[(b * NM + m) * DOC + tid];
}

// ---------------- mean-pool over rows (512 threads: 4-way row split) ----------------
__global__ __launch_bounds__(512) void pool_kernel(const float* __restrict__ X,
                                                   float* __restrict__ out,
                                                   int R, float inv) {
  __shared__ float part[4][128];
  const int b = blockIdx.x;
  const int d = threadIdx.x & 127, g = threadIdx.x >> 7;
  const int per = R >> 2;
  float acc = 0.f;
  for (int r = g * per; r < (g + 1) * per; ++r) acc += X[(b * R + r) * 128 + d];
  part[g][d] = acc;
  __syncthreads();
  if (g == 0)
    out[b * 128 + d] = (part[0][d] + part[1][d] + part[2][d] + part[3][d]) * inv;
}

// ---------------- folded U_m ----------------
__global__ __launch_bounds__(128) void um_kernel(
    const float* __restrict__ hmacs, const float* __restrict__ po,
    const float* __restrict__ pm, const float* __restrict__ A0,
    const float* __restrict__ Ab0, float* __restrict__ um) {
  __shared__ float v[384];
  const int b = blockIdx.y, m = blockIdx.x;
  const int j = threadIdx.x;
  v[j] = hmacs[(b * NM + m) * 128 + j];
  v[128 + j] = po[b * 128 + j];
  v[256 + j] = pm[b * 128 + j];
  __syncthreads();
  const float* a = A0 + j * 512 + 128;
  float acc = Ab0[j];
  for (int k = 0; k < 384; ++k) acc = fmaf(a[k], v[k], acc);
  um[(b * NM + m) * 128 + j] = acc;
}

// ---------------- actor via bf16 MFMA 16x16x32 (verified r6: absmax 0.0) ----------------
__global__ __launch_bounds__(256) void actor_mfma_kernel(
    const float* __restrict__ Uo, const float* __restrict__ Um,
    const float* __restrict__ A1, const float* __restrict__ Ab1,
    const float* __restrict__ A2, const float* __restrict__ Ab2,
    float* __restrict__ logits) {
  __shared__ short a1s[128 * 136];
  __shared__ float umv[128];
  const int tid = threadIdx.x;
  const int rbase = blockIdx.x * 64;       // flat row = b*16384 + m*512 + o
  const int b = rbase >> 14;
  const int m = (rbase & 16383) >> 9;
  #pragma unroll
  for (int it = 0; it < 16; ++it) {
    int f = it * 1024 + tid * 4;
    int c = f >> 7, k = f & 127;
    f32x4 v = *(const f32x4*)(A1 + c * 128 + k);
    s16x4 sv;
    sv[0] = f2bf(v[0]); sv[1] = f2bf(v[1]); sv[2] = f2bf(v[2]); sv[3] = f2bf(v[3]);
    *(s16x4*)&a1s[c * 136 + k] = sv;
  }
  if (tid < 128) umv[tid] = Um[(b * NM + m) * 128 + tid];
  __syncthreads();

  const int lane = tid & 63, w = tid >> 6;
  const int rowl = lane & 15, kg = lane >> 4;
  const float* uo = Uo + (rbase + w * 16 + rowl) * 128;
  bf16x8 af[4];
  #pragma unroll
  for (int kk = 0; kk < 4; ++kk) {
    int kb = kk * 32 + kg * 8;
    f32x4 u0 = *(const f32x4*)(uo + kb);
    f32x4 u1 = *(const f32x4*)(uo + kb + 4);
    #pragma unroll
    for (int e = 0; e < 4; ++e) af[kk][e]     = f2bf(fast_tanh(u0[e] + umv[kb + e]));
    #pragma unroll
    for (int e = 0; e < 4; ++e) af[kk][4 + e] = f2bf(fast_tanh(u1[e] + umv[kb + 4 + e]));
  }
  float partrow[4] = {0.f, 0.f, 0.f, 0.f};
  #pragma unroll
  for (int ct = 0; ct < 8; ++ct) {
    f32x4 acc = {0.f, 0.f, 0.f, 0.f};
    #pragma unroll
    for (int kk = 0; kk < 4; ++kk) {
      bf16x8 bf = *(const bf16x8*)&a1s[(ct * 16 + rowl) * 136 + kk * 32 + kg * 8];
      acc = __builtin_amdgcn_mfma_f32_16x16x32_bf16(af[kk], bf, acc, 0, 0, 0);
    }
    const int col = ct * 16 + rowl;
    const float ab = Ab1[col], a2c = A2[col];
    #pragma unroll
    for (int r = 0; r < 4; ++r) {
      float z2 = fast_tanh(acc[r] + ab);
      partrow[r] = fmaf(a2c, z2, partrow[r]);
    }
  }
  const float ab2 = Ab2[0];
  #pragma unroll
  for (int r = 0; r < 4; ++r) {
    float v = partrow[r];
    #pragma unroll
    for (int off = 1; off < 16; off <<= 1) v += __shfl_xor(v, off);
    if (rowl == 0) logits[rbase + w * 16 + kg * 4 + r] = v + ab2;
  }
}

// ---------------- masked log-softmax + gather + entropy (1024 threads) ----------------
__global__ __launch_bounds__(1024) void final_kernel(
    const float* __restrict__ logits, const void* __restrict__ maskp,
    const int* __restrict__ aidx, const int* __restrict__ flag,
    float* __restrict__ out) {
  __shared__ float sc[16], sc2[16];
  const int b = blockIdx.x;
  const int tid = threadIdx.x;
  const int lane = tid & 63, w = tid >> 6;
  const bool word_mode = (flag[0] == 0);
  const unsigned int* mw = (const unsigned int*)maskp;
  const unsigned char* mb = (const unsigned char*)maskp;
  const float* lg = logits + b * (NM * NO);
  float mx = -1e30f;
  for (int s = 0; s < 16; ++s) {
    int i = s * 1024 + tid;
    int o = i & 511, mm = i >> 9;
    int mofs = (b * NO + o) * NM + mm;
    bool msk = word_mode ? (mw[mofs] != 0u) : (mb[mofs] != 0);
    if (msk) mx = fmaxf(mx, lg[i]);
  }
  #pragma unroll
  for (int off = 32; off; off >>= 1) mx = fmaxf(mx, __shfl_down(mx, off));
  if (lane == 0) sc[w] = mx;
  __syncthreads();
  if (tid == 0) {
    float m2 = sc[0];
    for (int k = 1; k < 16; ++k) m2 = fmaxf(m2, sc[k]);
    sc[0] = m2;
  }
  __syncthreads();
  mx = sc[0];
  __syncthreads();
  float S = 0.f, T = 0.f;
  for (int s = 0; s < 16; ++s) {
    int i = s * 1024 + tid;
    int o = i & 511, mm = i >> 9;
    int mofs = (b * NO + o) * NM + mm;
    bool msk = word_mode ? (mw[mofs] != 0u) : (mb[mofs] != 0);
    if (msk) {
      float d = lg[i] - mx;
      float e = __expf(d);
      S += e;
      T = fmaf(e, d, T);
    }
  }
  #pragma unroll
  for (int off = 32; off; off >>= 1) { S += __shfl_down(S, off); T += __shfl_down(T, off); }
  if (lane == 0) { sc[w] = S; sc2[w] = T; }
  __syncthreads();
  if (tid == 0) {
    float St = 0.f, Tt = 0.f;
    for (int k = 0; k < 16; ++k) { St += sc[k]; Tt += sc2[k]; }
    float lS = logf(St);
    out[b] = lg[aidx[b]] - mx - lS;          // action_logprobs
    out[32 + b] = lS - Tt / St;              // dist_entropys
  }
}

// ---------------- critic MLP (per batch) ----------------
__global__ __launch_bounds__(128) void critic_kernel(
    const float* __restrict__ po, const float* __restrict__ pm,
    const float* __restrict__ C0, const float* __restrict__ Cb0,
    const float* __restrict__ C1, const float* __restrict__ Cb1,
    const float* __restrict__ C2, const float* __restrict__ Cb2,
    float* __restrict__ out) {
  __shared__ float v[256];
  __shared__ float z[128];
  __shared__ float sc[2];
  const int b = blockIdx.x;
  const int j = threadIdx.x;
  v[j] = po[b * 128 + j];
  v[128 + j] = pm[b * 128 + j];
  __syncthreads();
  float acc = Cb0[j];
  for (int k = 0; k < 256; ++k) acc = fmaf(C0[j * 256 + k], v[k], acc);
  z[j] = fast_tanh(acc);
  __syncthreads();
  acc = Cb1[j];
  for (int k = 0; k < 128; ++k) acc = fmaf(C1[j * 128 + k], z[k], acc);
  float z2 = fast_tanh(acc);
  float p = C2[j] * z2;
  #pragma unroll
  for (int off = 32; off; off >>= 1) p += __shfl_down(p, off);
  const int lane = j & 63, w = j >> 6;
  if (lane == 0) sc[w] = p;
  __syncthreads();
  if (j == 0) out[16 + b] = sc[0] + sc[1] + Cb2[0];   // state_values
}

extern "C" void kernel_launch(void* const* d_in, const int* in_sizes, int n_in,
                              void* d_out, int out_size, void* d_ws, size_t ws_size,
                              hipStream_t stream) {
  (void)in_sizes; (void)n_in; (void)out_size; (void)ws_size;
  const float* adj  = (const float*)d_in[0];
  const float* nop  = (const float*)d_in[1];
  const float* nmac = (const float*)d_in[2];
  const void*  maskp = d_in[3];
  const int*   aidx = (const int*)d_in[4];
  const float* Wtr  = (const float*)d_in[5];
  const float* btr  = (const float*)d_in[6];
  const float* W0   = (const float*)d_in[7];
  const float* b0   = (const float*)d_in[8];
  const float* W1   = (const float*)d_in[9];
  const float* b1   = (const float*)d_in[10];
  const float* Wp   = (const float*)d_in[11];
  const float* bp   = (const float*)d_in[12];
  const float* Wo   = (const float*)d_in[13];
  const float* Wm   = (const float*)d_in[14];
  const float* alo  = (const float*)d_in[15];
  const float* alm  = (const float*)d_in[16];
  const float* A0   = (const float*)d_in[17];
  const float* Ab0  = (const float*)d_in[18];
  const float* A1   = (const float*)d_in[19];
  const float* Ab1  = (const float*)d_in[20];
  const float* A2   = (const float*)d_in[21];
  const float* Ab2  = (const float*)d_in[22];
  const float* C0   = (const float*)d_in[23];
  const float* Cb0  = (const float*)d_in[24];
  const float* C1   = (const float*)d_in[25];
  const float* Cb1  = (const float*)d_in[26];
  const float* C2   = (const float*)d_in[27];
  const float* Cb2  = (const float*)d_in[28];

  float* ws     = (float*)d_ws;        // needs ~41 MiB
  float* x12    = ws + OFF_X12;
  float* hopes  = ws + OFF_HOPES;
  float* hopeG  = ws + OFF_HOPEG;
  float* hmac   = ws + OFF_HMAC;
  float* hmacs  = ws + OFF_HMACS;
  float* ao     = ws + OFF_AO;
  float* am     = ws + OFF_AM;
  float* po     = ws + OFF_PO;
  float* pm     = ws + OFF_PM;
  float* Uo     = ws + OFF_UO;
  float* Um     = ws + OFF_UM;
  float* logits = ws + OFF_LOG;
  int*   flag   = (int*)(ws + OFF_FLAG);
  float* outp   = (float*)d_out;

  probe_mask_kernel<<<1, 256, 0, stream>>>((const unsigned int*)maskp, flag);

  // external attention
  gemm_wave<2><<<dim3(16, 64), 256, 0, stream>>>(nop, Wtr, btr, x12, 1024, 128, 128, 128);
  attn_kernel<<<dim3(NH, BB), 256, 0, stream>>>(x12, W0, b0, W1, b1);
  gemm_wave<1><<<dim3(2, 128), 256, 0, stream>>>(x12, Wp, bp, hopes, 128, 1024, 1024, 1024);

  // GAT
  gemm_wave<1><<<dim3(2, 128), 256, 0, stream>>>(nop, Wo, nullptr, hopeG, 128, 128, 128, 128);
  gemm_xt<<<dim3(2, 8), 256, 0, stream>>>(nmac, Wm, nullptr, hmac, 512, 128, 64, 64, 64);
  rowdot<<<2048, 256, 0, stream>>>(hopeG, alo, ao, 8192);
  rowdot<<<128, 256, 0, stream>>>(hmac, alm, am, 512);
  gat_kernel<<<dim3(NM, BB), 128, 0, stream>>>(adj, ao, am, hopeG, hmac, hmacs);

  // pooling
  pool_kernel<<<16, 512, 0, stream>>>(hopes, po, 512, 1.0f / 512.0f);
  pool_kernel<<<16, 512, 0, stream>>>(hmacs, pm, 32, 1.0f / 32.0f);

  // actor (Uo aliases x12's region — x12 is dead after the proj GEMM above)
  gemm_wave<1><<<dim3(2, 128), 256, 0, stream>>>(hopes, A0, nullptr, Uo, 128, 128, 128, 512);
  um_kernel<<<dim3(NM, BB), 128, 0, stream>>>(hmacs, po, pm, A0, Ab0, Um);
  actor_mfma_kernel<<<4096, 256, 0, stream>>>(Uo, Um, A1, Ab1, A2, Ab2, logits);
  final_kernel<<<16, 1024, 0, stream>>>(logits, maskp, aidx, flag, outp);

  // critic
  critic_kernel<<<16, 128, 0, stream>>>(po, pm, C0, Cb0, C1, Cb1, C2, Cb2, outp);
}